// Round 2
// baseline (16076.550 us; speedup 1.0000x reference)
//
#include <hip/hip_runtime.h>
#include <math.h>

#define USE_FMA_DOT 1   // einsum dot rounding: 1 = Eigen-style fma chain, 0 = separate roundings

constexpr int BB  = 32;
constexpr int N0  = 2048;
constexpr int KNN = 32;
constexpr float SIGMA_ = 0.26f;
constexpr float BASELINE_ = 0.1f;
constexpr float SCALING_ = 10.0f;
constexpr float EPS_ = 1e-6f;

// embedding configs: cfg0 = initial od=32; cfg1..4 = stage out_dims 64,128,256,512
__device__ __constant__ const int c_OD[5]    = {32,64,128,256,512};
__device__ __constant__ const int c_FD[5]    = {11,22,43,86,171};
__device__ __constant__ const int c_FVOFF[5] = {0,11,33,76,162};
__device__ __constant__ const int c_OMOFF[5] = {0,32,96,224,480};
static const int h_FVOFF[5] = {0,11,33,76,162};
static const int h_OMOFF[5] = {0,32,96,224,480};

// ---------------- workspace layout (bytes) ----------------
constexpr size_t ALGN(size_t x){ return (x + 255) & ~(size_t)255; }
constexpr size_t SZ_FEAT  = (size_t)BB*2048*32*4;   // 8 MB (holds any stage's feat: all are 2M floats)
constexpr size_t OFF_FEATA = 0;
constexpr size_t OFF_FEATB = OFF_FEATA + SZ_FEAT;
constexpr size_t SZ_FEATS  = (size_t)BB*1024*32*4;  // 4 MB (B*S_out*C_in == 1M floats each stage)
constexpr size_t OFF_FEATS = OFF_FEATB + SZ_FEAT;
constexpr size_t SZ_KNNI   = (size_t)BB*1024*KNN*4; // 4 MB
constexpr size_t OFF_KNNI  = OFF_FEATS + SZ_FEATS;
constexpr size_t SZ_XYZ    = (size_t)BB*1024*3*4;
constexpr size_t OFF_XYZA  = OFF_KNNI + SZ_KNNI;
constexpr size_t OFF_XYZB  = OFF_XYZA + ALGN(SZ_XYZ);
constexpr size_t SZ_FPSI   = (size_t)BB*1024*4;
constexpr size_t OFF_FPSI  = OFF_XYZB + ALGN(SZ_XYZ);
constexpr size_t SZ_STATS  = 8192*8;                // f64: xs[32][32][3], xq, fs[32][32], fq
constexpr size_t OFF_STATS = OFF_FPSI + ALGN(SZ_FPSI);
constexpr size_t SZ_STATS0 = 192*8;
constexpr size_t OFF_STATS0= OFF_STATS + SZ_STATS;
constexpr size_t OFF_FV    = OFF_STATS0 + ALGN(SZ_STATS0);
constexpr size_t OFF_OMD   = OFF_FV  + ALGN(333*4);
constexpr size_t OFF_OMF   = OFF_OMD + ALGN(992*4);
constexpr size_t OFF_PAR0  = OFF_OMF + ALGN(992*4);
constexpr size_t OFF_PAR   = OFF_PAR0 + 256;
constexpr size_t WS_NEED   = OFF_PAR + 512;

// ---------------- exact-arithmetic helpers (match XLA CPU elementwise rounding) ----------------
__device__ __forceinline__ float sq3_ref(float x, float y, float z) {
#pragma clang fp contract(off)
  float a = x*x, b = y*y, c = z*z;
  return (a + b) + c;
}
__device__ __forceinline__ float dist3_ref(float ax,float ay,float az,float bx,float by,float bz){
#pragma clang fp contract(off)
  float dx = ax-bx, dy = ay-by, dz = az-bz;
  float a = dx*dx, b = dy*dy, c = dz*dz;
  return (a + b) + c;
}
__device__ __forceinline__ float knn_dist(float qx,float qy,float qz,float ssrc,
                                          float px,float py,float pz){
#pragma clang fp contract(off)
  float sdst = (px*px + py*py) + pz*pz;
#if USE_FMA_DOT
  float dot = __builtin_fmaf(qz, pz, __builtin_fmaf(qy, py, qx*px));
#else
  float dot = (qx*px + qy*py) + qz*pz;
#endif
  float m = -2.0f * dot;
  return (m + ssrc) + sdst;
}

// ---------------- table init (numpy linspace semantics in f64) ----------------
__global__ void k_init_tables(float* __restrict__ fv, int* __restrict__ omd, int* __restrict__ omf){
  for (int cfg = 0; cfg < 5; ++cfg){
    int od = c_OD[cfg], fd = c_FD[cfg], fn = fd*3;
    double stepv = 2.0 / (double)(fd + 1);
    for (int f = threadIdx.x; f < fd; f += blockDim.x)
      fv[c_FVOFF[cfg] + f] = (float)((double)(f+1) * stepv + (-1.0));
    double stepi = (double)(fn - 1) / (double)(od - 1);
    for (int j = threadIdx.x; j < od; j += blockDim.x){
      int q = (j == od-1) ? (fn-1) : (int)floor((double)j * stepi);
      omd[c_OMOFF[cfg] + j] = q / fd;
      omf[c_OMOFF[cfg] + j] = q - (q/fd)*fd;
    }
  }
}

// ---------------- initial gstd (per (b,c) sum/sumsq over N) ----------------
__global__ void k_stats0(const float* __restrict__ xyz, double* __restrict__ s0){
  int e = blockIdx.x, b = e/3, c = e%3, t = threadIdx.x;
  double s = 0.0, ss = 0.0;
  for (int n = t; n < N0; n += blockDim.x){
    double v = (double)xyz[((size_t)b*N0 + n)*3 + c];
    s += v; ss += v*v;
  }
  __shared__ double ls[256], lq[256];
  ls[t] = s; lq[t] = ss; __syncthreads();
  for (int w = 128; w > 0; w >>= 1){
    if (t < w){ ls[t] += ls[t+w]; lq[t] += lq[t+w]; }
    __syncthreads();
  }
  if (t == 0){ s0[e*2] = ls[0]; s0[e*2+1] = lq[0]; }
}

__global__ void k_finalize0(const double* __restrict__ s0, float* __restrict__ par0){
  __shared__ double acc[96];
  int t = threadIdx.x;
  if (t < 96){
    double s = s0[t*2], ss = s0[t*2+1];
    double var = (ss - s*s/(double)N0) / (double)(N0 - 1);
    acc[t] = sqrt(var < 0.0 ? 0.0 : var);
  }
  __syncthreads();
  if (t == 0){
    double g = 0.0;
    for (int i = 0; i < 96; ++i) g += acc[i];
    float gstd = (float)(g / 96.0);
    float asig = SIGMA_ * (1.0f + gstd);
    float dn = asig + EPS_;
    float blend = 1.0f / (1.0f + expf(-(gstd - BASELINE_)*SCALING_));
    par0[0] = 1.0f/dn; par0[1] = blend; par0[2] = 1.0f - blend;
  }
}

// ---------------- initial embedding: feat0[b,n,0..31] ----------------
__global__ void k_embed0(const float* __restrict__ xyz, float* __restrict__ feat,
                         const float* __restrict__ par0, const float* __restrict__ fv,
                         const int* __restrict__ omd, const int* __restrict__ omf){
  int e = blockIdx.x*blockDim.x + threadIdx.x;
  if (e >= BB*N0) return;
  float x0 = xyz[(size_t)e*3], x1 = xyz[(size_t)e*3+1], x2 = xyz[(size_t)e*3+2];
  float invdn = par0[0], blend = par0[1], omb = par0[2];
  float* out = &feat[(size_t)e*32];
  #pragma unroll 8
  for (int j = 0; j < 32; ++j){
    int dj = omd[j];
    float xv = (dj == 0) ? x0 : ((dj == 1) ? x1 : x2);
    float tt = (xv - fv[omf[j]]) * invdn;
    out[j] = blend*__expf(-0.5f*tt*tt) + omb*__cosf(tt);
  }
}

// ---------------- FPS: one block per batch, exact reference semantics ----------------
template<int PPT>
__launch_bounds__(256)
__global__ void k_fps(const float* __restrict__ xyz, float* __restrict__ xyz_out,
                      int* __restrict__ fps_idx){
  constexpr int N = PPT*256;
  constexpr int SOUT = N/2;
  int b = blockIdx.x, t = threadIdx.x;
  const float* xb = xyz + (size_t)b*N*3;
  __shared__ float xl[N*3];
  __shared__ float pval[2][4];
  __shared__ int   pidx[2][4];
  for (int i = t; i < N*3; i += 256) xl[i] = xb[i];
  __syncthreads();
  float px[PPT], py[PPT], pz[PPT], dist[PPT];
  #pragma unroll
  for (int u = 0; u < PPT; ++u){
    int i = t + 256*u;
    px[u] = xl[i*3]; py[u] = xl[i*3+1]; pz[u] = xl[i*3+2];
    dist[u] = INFINITY;
  }
  float cx = xl[0], cy = xl[1], cz = xl[2];
  if (t == 0){
    fps_idx[b*1024] = 0;
    size_t o = (size_t)b*SOUT*3;
    xyz_out[o] = cx; xyz_out[o+1] = cy; xyz_out[o+2] = cz;
  }
  int wave = t >> 6, lane = t & 63;
  for (int step = 1; step < SOUT; ++step){
    float bv; int bi;
    #pragma unroll
    for (int u = 0; u < PPT; ++u){
      float d = dist3_ref(px[u], py[u], pz[u], cx, cy, cz);
      float nd = fminf(dist[u], d);
      dist[u] = nd;
      if (u == 0){ bv = nd; bi = t; }
      else if (nd > bv){ bv = nd; bi = t + 256*u; }   // in-lane indices ascend with u -> first-max kept
    }
    #pragma unroll
    for (int m = 1; m < 64; m <<= 1){
      float ov = __shfl_xor(bv, m);
      int   oi = __shfl_xor(bi, m);
      if (ov > bv || (ov == bv && oi < bi)){ bv = ov; bi = oi; }
    }
    int pb = step & 1;
    if (lane == 0){ pval[pb][wave] = bv; pidx[pb][wave] = bi; }
    __syncthreads();
    float wv = pval[pb][0]; int wi = pidx[pb][0];
    #pragma unroll
    for (int w = 1; w < 4; ++w){
      float ov = pval[pb][w]; int oi = pidx[pb][w];
      if (ov > wv || (ov == wv && oi < wi)){ wv = ov; wi = oi; }
    }
    cx = xl[wi*3]; cy = xl[wi*3+1]; cz = xl[wi*3+2];
    if (t == 0){
      fps_idx[b*1024 + step] = wi;
      size_t o = (size_t)b*SOUT*3 + (size_t)step*3;
      xyz_out[o] = cx; xyz_out[o+1] = cy; xyz_out[o+2] = cz;
    }
  }
}

// ---------------- gather feat_s ----------------
__global__ void k_gather_fs(const float* __restrict__ feat, const int* __restrict__ fps_idx,
                            float* __restrict__ feat_s, int S_out, int C, int S_in){
  int e = blockIdx.x, b = e / S_out, s = e - b*S_out;
  int idx = fps_idx[b*1024 + s];
  const float* src = &feat[((size_t)b*S_in + idx)*C];
  float* dst = &feat_s[((size_t)b*S_out + s)*C];
  for (int c = threadIdx.x; c < C; c += blockDim.x) dst[c] = src[c];
}

// ---------------- KNN: exact top-k (ascending dist, ties -> smaller index) ----------------
__launch_bounds__(128)
__global__ void k_knn(const float* __restrict__ xyz, const float* __restrict__ xyz_s,
                      int* __restrict__ knn_idx, int N, int S_out){
  __shared__ float xl[2048*3];
  __shared__ float dl[KNN][129];
  __shared__ int   il[KNN][129];
  int nb = S_out / 128;
  int b = blockIdx.x / nb, chunk = blockIdx.x - b*nb;
  int t = threadIdx.x;
  const float* xb = xyz + (size_t)b*N*3;
  for (int i = t; i < N*3; i += 128) xl[i] = xb[i];
  int s = chunk*128 + t;
  const float* q = &xyz_s[((size_t)b*S_out + s)*3];
  float qx = q[0], qy = q[1], qz = q[2];
  float ssrc = sq3_ref(qx, qy, qz);
  #pragma unroll
  for (int k = 0; k < KNN; ++k) dl[k][t] = INFINITY;
  __syncthreads();
  float worst = INFINITY;
  for (int j = 0; j < N; ++j){
    float px = xl[j*3], py = xl[j*3+1], pz = xl[j*3+2];
    float d = knn_dist(qx, qy, qz, ssrc, px, py, pz);
    if (d < worst){
      int k = KNN-1;
      while (k > 0){
        float dk = dl[k-1][t];
        if (dk <= d) break;                 // ties: existing (smaller index) stays first
        dl[k][t] = dk; il[k][t] = il[k-1][t];
        --k;
      }
      dl[k][t] = d; il[k][t] = j;
      worst = dl[KNN-1][t];
    }
  }
  int* out = &knn_idx[((size_t)b*S_out + s)*KNN];
  #pragma unroll
  for (int k = 0; k < KNN; ++k) out[k] = il[k][t];
}

// ---------------- per-k stats (f64) for normalize stds + gstd algebra ----------------
__launch_bounds__(256)
__global__ void k_stats(const float* __restrict__ xyz, const float* __restrict__ xyz_s,
                        const float* __restrict__ feat, const float* __restrict__ feat_s,
                        const int* __restrict__ knn_idx, double* __restrict__ acc,
                        int S_in, int S_out, int C){
  int nb = S_out / 8;
  int b = blockIdx.x / nb, chunk = blockIdx.x - b*nb;
  int t = threadIdx.x, k = t & 31, sl = t >> 5;
  int s = chunk*8 + sl;
  int idx = knn_idx[((size_t)b*S_out + s)*KNN + k];
  const float* p  = &xyz[((size_t)b*S_in + idx)*3];
  const float* c0 = &xyz_s[((size_t)b*S_out + s)*3];
  double vs[8];
  #pragma unroll
  for (int c = 0; c < 3; ++c){
    float d = p[c] - c0[c];
    double dd = (double)d;
    vs[c] = dd; vs[3+c] = dd*dd;
  }
  const float* fp = &feat[((size_t)b*S_in + idx)*C];
  const float* fc = &feat_s[((size_t)b*S_out + s)*C];
  double fs = 0.0, fq = 0.0;
  for (int c = 0; c < C; ++c){
    float d = fp[c] - fc[c];
    double dd = (double)d;
    fs += dd; fq += dd*dd;
  }
  vs[6] = fs; vs[7] = fq;
  __shared__ double ls[256][8];
  #pragma unroll
  for (int v = 0; v < 8; ++v) ls[t][v] = vs[v];
  __syncthreads();
  int k2 = t & 31, v = t >> 5;
  double a = 0.0;
  #pragma unroll
  for (int s2 = 0; s2 < 8; ++s2) a += ls[k2 + 32*s2][v];
  double* tgt;
  if (v < 3)       tgt = &acc[((size_t)(b*32 + k2))*3 + v];
  else if (v < 6)  tgt = &acc[3072 + ((size_t)(b*32 + k2))*3 + (v-3)];
  else if (v == 6) tgt = &acc[6144 + b*32 + k2];
  else             tgt = &acc[7168 + b*32 + k2];
  atomicAdd(tgt, a);
}

// ---------------- finalize: stds (per-k), gstd, asig, blend ----------------
__launch_bounds__(256)
__global__ void k_finalize(const double* __restrict__ acc, float* __restrict__ par,
                           int S_out, int C){
  __shared__ double invx_d[32];
  __shared__ double bcstd[96];
  int t = threadIdx.x;
  if (t < 32){
    double S = 0.0, Q = 0.0;
    for (int b = 0; b < BB; ++b)
      #pragma unroll
      for (int c = 0; c < 3; ++c){
        S += acc[((size_t)(b*32 + t))*3 + c];
        Q += acc[3072 + ((size_t)(b*32 + t))*3 + c];
      }
    double n = (double)BB * S_out * 3;
    double var = (Q - S*S/n) / (n - 1.0);
    float sd = (float)sqrt(var < 0.0 ? 0.0 : var);
    sd = fmaxf(sd, 1e-5f);
    par[t] = sd;                       // divisor for xyz normalize (exact f32 div later)
    invx_d[t] = 1.0 / (double)sd;
  } else if (t < 64){
    int k = t - 32;
    double S = 0.0, Q = 0.0;
    for (int b = 0; b < BB; ++b){
      S += acc[6144 + b*32 + k];
      Q += acc[7168 + b*32 + k];
    }
    double n = (double)BB * S_out * C;
    double var = (Q - S*S/n) / (n - 1.0);
    float sd = (float)sqrt(var < 0.0 ? 0.0 : var);
    sd = fmaxf(sd, 1e-5f);
    par[32 + k] = 1.0f / sd;           // reciprocal for feat normalize
  }
  __syncthreads();
  if (t < 96){
    int b = t/3, c = t - (t/3)*3;
    double S1 = 0.0, S2 = 0.0;
    for (int k = 0; k < 32; ++k){
      double iv = invx_d[k];
      S1 += acc[((size_t)(b*32 + k))*3 + c] * iv;
      S2 += acc[3072 + ((size_t)(b*32 + k))*3 + c] * iv*iv;
    }
    double m = (double)S_out * KNN;
    double var = (S2 - S1*S1/m) / (m - 1.0);
    bcstd[t] = sqrt(var < 0.0 ? 0.0 : var);
  }
  __syncthreads();
  if (t == 0){
    double g = 0.0;
    for (int i = 0; i < 96; ++i) g += bcstd[i];
    float gstd = (float)(g / 96.0);
    float asig = SIGMA_ * (1.0f + gstd);
    float dn = asig + EPS_;
    float blend = 1.0f / (1.0f + expf(-(gstd - BASELINE_)*SCALING_));
    par[64] = 1.0f/dn; par[65] = blend; par[66] = 1.0f - blend;
  }
}

// ---------------- main: pe + feature concat + (mean+max over K) + gelu ----------------
__launch_bounds__(512)
__global__ void k_main(const float* __restrict__ xyz, const float* __restrict__ xyz_s,
                       const float* __restrict__ feat, const float* __restrict__ feat_s,
                       const int* __restrict__ knn_idx, const float* __restrict__ par,
                       const float* __restrict__ fv, const int* __restrict__ omd,
                       const int* __restrict__ omf, float* __restrict__ feat_out,
                       int S_in, int S_out, int C){
  int b = blockIdx.x / S_out, s = blockIdx.x - b*S_out;
  int t = threadIdx.x, Cout = blockDim.x;
  __shared__ float nx[KNN][4];
  __shared__ int idxs[KNN];
  const float* cs = &xyz_s[((size_t)b*S_out + s)*3];
  for (int e = t; e < 96; e += Cout){
    int k = e/3, c = e - k*3;
    int ix = knn_idx[((size_t)b*S_out + s)*KNN + k];
    if (c == 0) idxs[k] = ix;
    float p = xyz[((size_t)b*S_in + ix)*3 + c];
    nx[k][c] = (p - cs[c]) / par[k];   // exact f32 division, matches reference d/std
  }
  __syncthreads();
  int dimj = omd[t], fij = omf[t];
  float fvv = fv[fij];
  float invdn = par[64], blend = par[65], omb = par[66];
  const float* fsrow = &feat_s[((size_t)b*S_out + s)*C];
  bool lo = (t < C);
  float fsj = lo ? fsrow[t] : fsrow[t - C];
  const float* fb = &feat[(size_t)b*S_in*C];
  float acc = 0.0f, mx = -INFINITY;
  for (int k = 0; k < KNN; ++k){
    float fc;
    if (lo){
      float f = fb[(size_t)idxs[k]*C + t];
      fc = (f - fsj) * par[32 + k];
    } else {
      fc = fsj;
    }
    float xv = nx[k][dimj];
    float tt = (xv - fvv) * invdn;
    float pe = blend*__expf(-0.5f*tt*tt) + omb*__cosf(tt);
    float w = (fc + pe) * pe;
    acc += w;
    mx = fmaxf(mx, w);
  }
  float pooled = acc * (1.0f/KNN) + mx;
  float g = 0.5f * pooled * (1.0f + erff(pooled / 1.41421356237f));
  feat_out[((size_t)b*S_out + s)*(size_t)(2*C) + t] = g;
}

// ---------------- per-stage output: max & mean over S ----------------
__global__ void k_stageout(const float* __restrict__ feat, float* __restrict__ out,
                           int S, int C, int off){
  int b = blockIdx.x;
  int c = blockIdx.y*64 + threadIdx.x;
  const float* f = &feat[(size_t)b*S*C + c];
  float mx = -INFINITY;
  double sm = 0.0;
  for (int s = 0; s < S; ++s){
    float v = f[(size_t)s*C];
    mx = fmaxf(mx, v);
    sm += (double)v;
  }
  out[(size_t)b*1920 + off + c] = mx;
  out[(size_t)b*1920 + off + C + c] = (float)(sm / (double)S);
}

// ---------------- host ----------------
extern "C" void kernel_launch(void* const* d_in, const int* in_sizes, int n_in,
                              void* d_out, int out_size, void* d_ws, size_t ws_size,
                              hipStream_t stream){
  if (ws_size < WS_NEED) return;
  const float* xyz0 = (const float*)d_in[0];
  float* out = (float*)d_out;
  char* ws = (char*)d_ws;

  float*  featA = (float*)(ws + OFF_FEATA);
  float*  featB = (float*)(ws + OFF_FEATB);
  float*  feats = (float*)(ws + OFF_FEATS);
  int*    knni  = (int*)  (ws + OFF_KNNI);
  float*  xyzA  = (float*)(ws + OFF_XYZA);
  float*  xyzB  = (float*)(ws + OFF_XYZB);
  int*    fpsi  = (int*)  (ws + OFF_FPSI);
  double* stats = (double*)(ws + OFF_STATS);
  double* s0    = (double*)(ws + OFF_STATS0);
  float*  fv    = (float*)(ws + OFF_FV);
  int*    omd   = (int*)  (ws + OFF_OMD);
  int*    omf   = (int*)  (ws + OFF_OMF);
  float*  par0  = (float*)(ws + OFF_PAR0);
  float*  par   = (float*)(ws + OFF_PAR);

  k_init_tables<<<1, 256, 0, stream>>>(fv, omd, omf);
  k_stats0<<<96, 256, 0, stream>>>(xyz0, s0);
  k_finalize0<<<1, 128, 0, stream>>>(s0, par0);
  k_embed0<<<(BB*N0)/256, 256, 0, stream>>>(xyz0, featA, par0, fv, omd, omf);

  const float* xin = xyz0;
  float* feat_in  = featA;
  float* feat_out = featB;
  const int off_[4] = {0, 128, 384, 896};

  for (int st = 0; st < 4; ++st){
    int Sin = 2048 >> st, Sout = 1024 >> st, C = 32 << st, Cout = 2*C, cfg = st + 1;
    float* xout = (st & 1) ? xyzB : xyzA;

    if      (st == 0) k_fps<8><<<BB, 256, 0, stream>>>(xin, xout, fpsi);
    else if (st == 1) k_fps<4><<<BB, 256, 0, stream>>>(xin, xout, fpsi);
    else if (st == 2) k_fps<2><<<BB, 256, 0, stream>>>(xin, xout, fpsi);
    else              k_fps<1><<<BB, 256, 0, stream>>>(xin, xout, fpsi);

    int gfs_bs = (C < 64) ? 64 : ((C > 256) ? 256 : C);
    k_gather_fs<<<BB*Sout, gfs_bs, 0, stream>>>(feat_in, fpsi, feats, Sout, C, Sin);
    k_knn<<<BB*(Sout/128), 128, 0, stream>>>(xin, xout, knni, Sin, Sout);
    hipMemsetAsync(ws + OFF_STATS, 0, SZ_STATS, stream);
    k_stats<<<BB*(Sout/8), 256, 0, stream>>>(xin, xout, feat_in, feats, knni, stats, Sin, Sout, C);
    k_finalize<<<1, 256, 0, stream>>>(stats, par, Sout, C);
    k_main<<<BB*Sout, Cout, 0, stream>>>(xin, xout, feat_in, feats, knni, par,
                                         fv + h_FVOFF[cfg], omd + h_OMOFF[cfg],
                                         omf + h_OMOFF[cfg], feat_out, Sin, Sout, C);
    k_stageout<<<dim3(BB, Cout/64), 64, 0, stream>>>(feat_out, out, Sout, Cout, off_[st]);

    xin = xout;
    float* t2 = feat_in; feat_in = feat_out; feat_out = t2;
  }
}

// Round 4
// 4288.158 us; speedup vs baseline: 3.7491x; 3.7491x over previous
//
#include <hip/hip_runtime.h>
#include <math.h>

#define USE_FMA_DOT 1   // einsum dot rounding: 1 = Eigen-style fma chain, 0 = separate roundings

constexpr int BB  = 32;
constexpr int N0  = 2048;
constexpr int KNN = 32;
constexpr float SIGMA_ = 0.26f;
constexpr float BASELINE_ = 0.1f;
constexpr float SCALING_ = 10.0f;
constexpr float EPS_ = 1e-6f;

// embedding configs: cfg0 = initial od=32; cfg1..4 = stage out_dims 64,128,256,512
__device__ __constant__ const int c_OD[5]    = {32,64,128,256,512};
__device__ __constant__ const int c_FD[5]    = {11,22,43,86,171};
__device__ __constant__ const int c_FVOFF[5] = {0,11,33,76,162};
__device__ __constant__ const int c_OMOFF[5] = {0,32,96,224,480};
static const int h_FVOFF[5] = {0,11,33,76,162};
static const int h_OMOFF[5] = {0,32,96,224,480};

// ---------------- workspace layout (bytes) ----------------
constexpr size_t ALGN(size_t x){ return (x + 255) & ~(size_t)255; }
constexpr size_t SZ_FEAT  = (size_t)BB*2048*32*4;   // 8 MB (holds any stage's feat: all are 2M floats)
constexpr size_t OFF_FEATA = 0;
constexpr size_t OFF_FEATB = OFF_FEATA + SZ_FEAT;
constexpr size_t SZ_FEATS  = (size_t)BB*1024*32*4;  // 4 MB (B*S_out*C_in == 1M floats each stage)
constexpr size_t OFF_FEATS = OFF_FEATB + SZ_FEAT;
constexpr size_t SZ_KNNI   = (size_t)BB*1024*KNN*4; // 4 MB
constexpr size_t OFF_KNNI  = OFF_FEATS + SZ_FEATS;
constexpr size_t SZ_XYZ    = (size_t)BB*1024*3*4;
constexpr size_t OFF_XYZA  = OFF_KNNI + SZ_KNNI;
constexpr size_t OFF_XYZB  = OFF_XYZA + ALGN(SZ_XYZ);
constexpr size_t SZ_FPSI   = (size_t)BB*1024*4;
constexpr size_t OFF_FPSI  = OFF_XYZB + ALGN(SZ_XYZ);
constexpr size_t SZ_STATS  = 8192*8;                // f64: xs[32][32][3], xq, fs[32][32], fq
constexpr size_t OFF_STATS = OFF_FPSI + ALGN(SZ_FPSI);
constexpr size_t SZ_STATS0 = 192*8;
constexpr size_t OFF_STATS0= OFF_STATS + SZ_STATS;
constexpr size_t OFF_FV    = OFF_STATS0 + ALGN(SZ_STATS0);
constexpr size_t OFF_OMD   = OFF_FV  + ALGN(333*4);
constexpr size_t OFF_OMF   = OFF_OMD + ALGN(992*4);
constexpr size_t OFF_PAR0  = OFF_OMF + ALGN(992*4);
constexpr size_t OFF_PAR   = OFF_PAR0 + 256;
constexpr size_t WS_NEED   = OFF_PAR + 512;

// ---------------- exact-arithmetic helpers (match XLA CPU elementwise rounding) ----------------
__device__ __forceinline__ float sq3_ref(float x, float y, float z) {
#pragma clang fp contract(off)
  float a = x*x, b = y*y, c = z*z;
  return (a + b) + c;
}
__device__ __forceinline__ float dist3_ref(float ax,float ay,float az,float bx,float by,float bz){
#pragma clang fp contract(off)
  float dx = ax-bx, dy = ay-by, dz = az-bz;
  float a = dx*dx, b = dy*dy, c = dz*dz;
  return (a + b) + c;
}
__device__ __forceinline__ float knn_dist(float qx,float qy,float qz,float ssrc,
                                          float px,float py,float pz){
#pragma clang fp contract(off)
  float sdst = (px*px + py*py) + pz*pz;
#if USE_FMA_DOT
  float dot = __builtin_fmaf(qz, pz, __builtin_fmaf(qy, py, qx*px));
#else
  float dot = (qx*px + qy*py) + qz*pz;
#endif
  float m = -2.0f * dot;
  return (m + ssrc) + sdst;
}

// ---------------- table init (numpy linspace semantics in f64) ----------------
__global__ void k_init_tables(float* __restrict__ fv, int* __restrict__ omd, int* __restrict__ omf){
  for (int cfg = 0; cfg < 5; ++cfg){
    int od = c_OD[cfg], fd = c_FD[cfg], fn = fd*3;
    double stepv = 2.0 / (double)(fd + 1);
    for (int f = threadIdx.x; f < fd; f += blockDim.x)
      fv[c_FVOFF[cfg] + f] = (float)((double)(f+1) * stepv + (-1.0));
    double stepi = (double)(fn - 1) / (double)(od - 1);
    for (int j = threadIdx.x; j < od; j += blockDim.x){
      int q = (j == od-1) ? (fn-1) : (int)floor((double)j * stepi);
      omd[c_OMOFF[cfg] + j] = q / fd;
      omf[c_OMOFF[cfg] + j] = q - (q/fd)*fd;
    }
  }
}

// ---------------- initial gstd (per (b,c) sum/sumsq over N) ----------------
__global__ void k_stats0(const float* __restrict__ xyz, double* __restrict__ s0){
  int e = blockIdx.x, b = e/3, c = e%3, t = threadIdx.x;
  double s = 0.0, ss = 0.0;
  for (int n = t; n < N0; n += blockDim.x){
    double v = (double)xyz[((size_t)b*N0 + n)*3 + c];
    s += v; ss += v*v;
  }
  __shared__ double ls[256], lq[256];
  ls[t] = s; lq[t] = ss; __syncthreads();
  for (int w = 128; w > 0; w >>= 1){
    if (t < w){ ls[t] += ls[t+w]; lq[t] += lq[t+w]; }
    __syncthreads();
  }
  if (t == 0){ s0[e*2] = ls[0]; s0[e*2+1] = lq[0]; }
}

__global__ void k_finalize0(const double* __restrict__ s0, float* __restrict__ par0){
  __shared__ double acc[96];
  int t = threadIdx.x;
  if (t < 96){
    double s = s0[t*2], ss = s0[t*2+1];
    double var = (ss - s*s/(double)N0) / (double)(N0 - 1);
    acc[t] = sqrt(var < 0.0 ? 0.0 : var);
  }
  __syncthreads();
  if (t == 0){
    double g = 0.0;
    for (int i = 0; i < 96; ++i) g += acc[i];
    float gstd = (float)(g / 96.0);
    float asig = SIGMA_ * (1.0f + gstd);
    float dn = asig + EPS_;
    float blend = 1.0f / (1.0f + expf(-(gstd - BASELINE_)*SCALING_));
    par0[0] = 1.0f/dn; par0[1] = blend; par0[2] = 1.0f - blend;
  }
}

// ---------------- initial embedding: feat0[b,n,0..31] ----------------
__global__ void k_embed0(const float* __restrict__ xyz, float* __restrict__ feat,
                         const float* __restrict__ par0, const float* __restrict__ fv,
                         const int* __restrict__ omd, const int* __restrict__ omf){
  int e = blockIdx.x*blockDim.x + threadIdx.x;
  if (e >= BB*N0) return;
  float x0 = xyz[(size_t)e*3], x1 = xyz[(size_t)e*3+1], x2 = xyz[(size_t)e*3+2];
  float invdn = par0[0], blend = par0[1], omb = par0[2];
  float* out = &feat[(size_t)e*32];
  #pragma unroll 8
  for (int j = 0; j < 32; ++j){
    int dj = omd[j];
    float xv = (dj == 0) ? x0 : ((dj == 1) ? x1 : x2);
    float tt = (xv - fv[omf[j]]) * invdn;
    out[j] = blend*__expf(-0.5f*tt*tt) + omb*__cosf(tt);
  }
}

// ---------------- FPS: one block per batch, exact reference semantics ----------------
template<int PPT>
__launch_bounds__(256)
__global__ void k_fps(const float* __restrict__ xyz, float* __restrict__ xyz_out,
                      int* __restrict__ fps_idx){
  constexpr int N = PPT*256;
  constexpr int SOUT = N/2;
  int b = blockIdx.x, t = threadIdx.x;
  const float* xb = xyz + (size_t)b*N*3;
  __shared__ float xl[N*3];
  __shared__ float pval[2][4];
  __shared__ int   pidx[2][4];
  for (int i = t; i < N*3; i += 256) xl[i] = xb[i];
  __syncthreads();
  float px[PPT], py[PPT], pz[PPT], dist[PPT];
  #pragma unroll
  for (int u = 0; u < PPT; ++u){
    int i = t + 256*u;
    px[u] = xl[i*3]; py[u] = xl[i*3+1]; pz[u] = xl[i*3+2];
    dist[u] = INFINITY;
  }
  float cx = xl[0], cy = xl[1], cz = xl[2];
  if (t == 0){
    fps_idx[b*1024] = 0;
    size_t o = (size_t)b*SOUT*3;
    xyz_out[o] = cx; xyz_out[o+1] = cy; xyz_out[o+2] = cz;
  }
  int wave = t >> 6, lane = t & 63;
  for (int step = 1; step < SOUT; ++step){
    float bv; int bi;
    #pragma unroll
    for (int u = 0; u < PPT; ++u){
      float d = dist3_ref(px[u], py[u], pz[u], cx, cy, cz);
      float nd = fminf(dist[u], d);
      dist[u] = nd;
      if (u == 0){ bv = nd; bi = t; }
      else if (nd > bv){ bv = nd; bi = t + 256*u; }   // in-lane indices ascend with u -> first-max kept
    }
    #pragma unroll
    for (int m = 1; m < 64; m <<= 1){
      float ov = __shfl_xor(bv, m);
      int   oi = __shfl_xor(bi, m);
      if (ov > bv || (ov == bv && oi < bi)){ bv = ov; bi = oi; }
    }
    int pb = step & 1;
    if (lane == 0){ pval[pb][wave] = bv; pidx[pb][wave] = bi; }
    __syncthreads();
    float wv = pval[pb][0]; int wi = pidx[pb][0];
    #pragma unroll
    for (int w = 1; w < 4; ++w){
      float ov = pval[pb][w]; int oi = pidx[pb][w];
      if (ov > wv || (ov == wv && oi < wi)){ wv = ov; wi = oi; }
    }
    cx = xl[wi*3]; cy = xl[wi*3+1]; cz = xl[wi*3+2];
    if (t == 0){
      fps_idx[b*1024 + step] = wi;
      size_t o = (size_t)b*SOUT*3 + (size_t)step*3;
      xyz_out[o] = cx; xyz_out[o+1] = cy; xyz_out[o+2] = cz;
    }
  }
}

// ---------------- gather feat_s ----------------
__global__ void k_gather_fs(const float* __restrict__ feat, const int* __restrict__ fps_idx,
                            float* __restrict__ feat_s, int S_out, int C, int S_in){
  int e = blockIdx.x, b = e / S_out, s = e - b*S_out;
  int idx = fps_idx[b*1024 + s];
  const float* src = &feat[((size_t)b*S_in + idx)*C];
  float* dst = &feat_s[((size_t)b*S_out + s)*C];
  for (int c = threadIdx.x; c < C; c += blockDim.x) dst[c] = src[c];
}

// ---------------- KNN v2: one wave per query, branchless exact 32-round extraction ----------------
// key = (monotone_bits(dist) << 32) | j  -> ascending u64 order == lax.top_k order
// (dist ascending, ties -> smaller index). Distance arithmetic identical to v1.
template<int N>
__launch_bounds__(256)
__global__ void k_knn2(const float* __restrict__ xyz, const float* __restrict__ xyz_s,
                       int* __restrict__ knn_idx, int S_out){
  constexpr int NL = N / 64;       // candidates per lane
  constexpr int QB = 16;           // queries per block (4 waves x 4 queries)
  constexpr int QW = QB / 4;
  __shared__ float xl[N*3];
  int nb = S_out / QB;
  int b = blockIdx.x / nb, chunk = blockIdx.x - b*nb;
  int t = threadIdx.x, w = t >> 6, lane = t & 63;
  const float* xb = xyz + (size_t)b*N*3;
  for (int i = t; i < N*3; i += 256) xl[i] = xb[i];
  __syncthreads();
  for (int r = 0; r < QW; ++r){
    int s = chunk*QB + w*QW + r;
    const float* q = &xyz_s[((size_t)b*S_out + s)*3];
    float qx = q[0], qy = q[1], qz = q[2];
    float ssrc = sq3_ref(qx, qy, qz);
    unsigned long long cur[NL];
    #pragma unroll
    for (int i = 0; i < NL; ++i){
      int j = i*64 + lane;
      float d = knn_dist(qx, qy, qz, ssrc, xl[j*3], xl[j*3+1], xl[j*3+2]);
      unsigned u = __float_as_uint(d);
      u ^= (unsigned)((int)u >> 31) | 0x80000000u;   // monotone float->uint
      cur[i] = ((unsigned long long)u << 32) | (unsigned)j;
    }
    unsigned long long keep = 0;
    for (int kr = 0; kr < KNN; ++kr){
      unsigned long long m = cur[0];
      #pragma unroll
      for (int i = 1; i < NL; ++i) m = (cur[i] < m) ? cur[i] : m;
      #pragma unroll
      for (int msk = 1; msk < 64; msk <<= 1){
        unsigned long long o = __shfl_xor(m, msk);
        m = (o < m) ? o : m;
      }
      #pragma unroll
      for (int i = 0; i < NL; ++i) if (cur[i] == m) cur[i] = ~0ULL;  // unique (idx in key)
      if (lane == kr) keep = m;
    }
    if (lane < KNN)
      knn_idx[((size_t)b*S_out + s)*KNN + lane] = (int)(unsigned)(keep & 0xFFFFFFFFULL);
  }
}

// ---------------- per-k stats (f64) for normalize stds + gstd algebra ----------------
__launch_bounds__(256)
__global__ void k_stats(const float* __restrict__ xyz, const float* __restrict__ xyz_s,
                        const float* __restrict__ feat, const float* __restrict__ feat_s,
                        const int* __restrict__ knn_idx, double* __restrict__ acc,
                        int S_in, int S_out, int C){
  int nb = S_out / 8;
  int b = blockIdx.x / nb, chunk = blockIdx.x - b*nb;
  int t = threadIdx.x, k = t & 31, sl = t >> 5;
  int s = chunk*8 + sl;
  int idx = knn_idx[((size_t)b*S_out + s)*KNN + k];
  const float* p  = &xyz[((size_t)b*S_in + idx)*3];
  const float* c0 = &xyz_s[((size_t)b*S_out + s)*3];
  double vs[8];
  #pragma unroll
  for (int c = 0; c < 3; ++c){
    float d = p[c] - c0[c];
    double dd = (double)d;
    vs[c] = dd; vs[3+c] = dd*dd;
  }
  const float* fp = &feat[((size_t)b*S_in + idx)*C];
  const float* fc = &feat_s[((size_t)b*S_out + s)*C];
  double fs = 0.0, fq = 0.0;
  for (int c = 0; c < C; ++c){
    float d = fp[c] - fc[c];
    double dd = (double)d;
    fs += dd; fq += dd*dd;
  }
  vs[6] = fs; vs[7] = fq;
  __shared__ double ls[256][8];
  #pragma unroll
  for (int v = 0; v < 8; ++v) ls[t][v] = vs[v];
  __syncthreads();
  int k2 = t & 31, v = t >> 5;
  double a = 0.0;
  #pragma unroll
  for (int s2 = 0; s2 < 8; ++s2) a += ls[k2 + 32*s2][v];
  double* tgt;
  if (v < 3)       tgt = &acc[((size_t)(b*32 + k2))*3 + v];
  else if (v < 6)  tgt = &acc[3072 + ((size_t)(b*32 + k2))*3 + (v-3)];
  else if (v == 6) tgt = &acc[6144 + b*32 + k2];
  else             tgt = &acc[7168 + b*32 + k2];
  atomicAdd(tgt, a);
}

// ---------------- finalize: stds (per-k), gstd, asig, blend ----------------
__launch_bounds__(256)
__global__ void k_finalize(const double* __restrict__ acc, float* __restrict__ par,
                           int S_out, int C){
  __shared__ double invx_d[32];
  __shared__ double bcstd[96];
  int t = threadIdx.x;
  if (t < 32){
    double S = 0.0, Q = 0.0;
    for (int b = 0; b < BB; ++b)
      #pragma unroll
      for (int c = 0; c < 3; ++c){
        S += acc[((size_t)(b*32 + t))*3 + c];
        Q += acc[3072 + ((size_t)(b*32 + t))*3 + c];
      }
    double n = (double)BB * S_out * 3;
    double var = (Q - S*S/n) / (n - 1.0);
    float sd = (float)sqrt(var < 0.0 ? 0.0 : var);
    sd = fmaxf(sd, 1e-5f);
    par[t] = sd;                       // divisor for xyz normalize (exact f32 div later)
    invx_d[t] = 1.0 / (double)sd;
  } else if (t < 64){
    int k = t - 32;
    double S = 0.0, Q = 0.0;
    for (int b = 0; b < BB; ++b){
      S += acc[6144 + b*32 + k];
      Q += acc[7168 + b*32 + k];
    }
    double n = (double)BB * S_out * C;
    double var = (Q - S*S/n) / (n - 1.0);
    float sd = (float)sqrt(var < 0.0 ? 0.0 : var);
    sd = fmaxf(sd, 1e-5f);
    par[32 + k] = 1.0f / sd;           // reciprocal for feat normalize
  }
  __syncthreads();
  if (t < 96){
    int b = t/3, c = t - (t/3)*3;
    double S1 = 0.0, S2 = 0.0;
    for (int k = 0; k < 32; ++k){
      double iv = invx_d[k];
      S1 += acc[((size_t)(b*32 + k))*3 + c] * iv;
      S2 += acc[3072 + ((size_t)(b*32 + k))*3 + c] * iv*iv;
    }
    double m = (double)S_out * KNN;
    double var = (S2 - S1*S1/m) / (m - 1.0);
    bcstd[t] = sqrt(var < 0.0 ? 0.0 : var);
  }
  __syncthreads();
  if (t == 0){
    double g = 0.0;
    for (int i = 0; i < 96; ++i) g += bcstd[i];
    float gstd = (float)(g / 96.0);
    float asig = SIGMA_ * (1.0f + gstd);
    float dn = asig + EPS_;
    float blend = 1.0f / (1.0f + expf(-(gstd - BASELINE_)*SCALING_));
    par[64] = 1.0f/dn; par[65] = blend; par[66] = 1.0f - blend;
  }
}

// ---------------- main: pe + feature concat + (mean+max over K) + gelu ----------------
__launch_bounds__(512)
__global__ void k_main(const float* __restrict__ xyz, const float* __restrict__ xyz_s,
                       const float* __restrict__ feat, const float* __restrict__ feat_s,
                       const int* __restrict__ knn_idx, const float* __restrict__ par,
                       const float* __restrict__ fv, const int* __restrict__ omd,
                       const int* __restrict__ omf, float* __restrict__ feat_out,
                       int S_in, int S_out, int C){
  int b = blockIdx.x / S_out, s = blockIdx.x - b*S_out;
  int t = threadIdx.x, Cout = blockDim.x;
  __shared__ float nx[KNN][4];
  __shared__ int idxs[KNN];
  const float* cs = &xyz_s[((size_t)b*S_out + s)*3];
  for (int e = t; e < 96; e += Cout){
    int k = e/3, c = e - k*3;
    int ix = knn_idx[((size_t)b*S_out + s)*KNN + k];
    if (c == 0) idxs[k] = ix;
    float p = xyz[((size_t)b*S_in + ix)*3 + c];
    nx[k][c] = (p - cs[c]) / par[k];   // exact f32 division, matches reference d/std
  }
  __syncthreads();
  int dimj = omd[t], fij = omf[t];
  float fvv = fv[fij];
  float invdn = par[64], blend = par[65], omb = par[66];
  const float* fsrow = &feat_s[((size_t)b*S_out + s)*C];
  bool lo = (t < C);
  float fsj = lo ? fsrow[t] : fsrow[t - C];
  const float* fb = &feat[(size_t)b*S_in*C];
  float acc = 0.0f, mx = -INFINITY;
  for (int k = 0; k < KNN; ++k){
    float fc;
    if (lo){
      float f = fb[(size_t)idxs[k]*C + t];
      fc = (f - fsj) * par[32 + k];
    } else {
      fc = fsj;
    }
    float xv = nx[k][dimj];
    float tt = (xv - fvv) * invdn;
    float pe = blend*__expf(-0.5f*tt*tt) + omb*__cosf(tt);
    float w = (fc + pe) * pe;
    acc += w;
    mx = fmaxf(mx, w);
  }
  float pooled = acc * (1.0f/KNN) + mx;
  float g = 0.5f * pooled * (1.0f + erff(pooled / 1.41421356237f));
  feat_out[((size_t)b*S_out + s)*(size_t)(2*C) + t] = g;
}

// ---------------- per-stage output: max & mean over S ----------------
__global__ void k_stageout(const float* __restrict__ feat, float* __restrict__ out,
                           int S, int C, int off){
  int b = blockIdx.x;
  int c = blockIdx.y*64 + threadIdx.x;
  const float* f = &feat[(size_t)b*S*C + c];
  float mx = -INFINITY;
  double sm = 0.0;
  for (int s = 0; s < S; ++s){
    float v = f[(size_t)s*C];
    mx = fmaxf(mx, v);
    sm += (double)v;
  }
  out[(size_t)b*1920 + off + c] = mx;
  out[(size_t)b*1920 + off + C + c] = (float)(sm / (double)S);
}

// ---------------- host ----------------
extern "C" void kernel_launch(void* const* d_in, const int* in_sizes, int n_in,
                              void* d_out, int out_size, void* d_ws, size_t ws_size,
                              hipStream_t stream){
  if (ws_size < WS_NEED) return;
  const float* xyz0 = (const float*)d_in[0];
  float* out = (float*)d_out;
  char* ws = (char*)d_ws;

  float*  featA = (float*)(ws + OFF_FEATA);
  float*  featB = (float*)(ws + OFF_FEATB);
  float*  feats = (float*)(ws + OFF_FEATS);
  int*    knni  = (int*)  (ws + OFF_KNNI);
  float*  xyzA  = (float*)(ws + OFF_XYZA);
  float*  xyzB  = (float*)(ws + OFF_XYZB);
  int*    fpsi  = (int*)  (ws + OFF_FPSI);
  double* stats = (double*)(ws + OFF_STATS);
  double* s0    = (double*)(ws + OFF_STATS0);
  float*  fv    = (float*)(ws + OFF_FV);
  int*    omd   = (int*)  (ws + OFF_OMD);
  int*    omf   = (int*)  (ws + OFF_OMF);
  float*  par0  = (float*)(ws + OFF_PAR0);
  float*  par   = (float*)(ws + OFF_PAR);

  k_init_tables<<<1, 256, 0, stream>>>(fv, omd, omf);
  k_stats0<<<96, 256, 0, stream>>>(xyz0, s0);
  k_finalize0<<<1, 128, 0, stream>>>(s0, par0);
  k_embed0<<<(BB*N0)/256, 256, 0, stream>>>(xyz0, featA, par0, fv, omd, omf);

  const float* xin = xyz0;
  float* feat_in  = featA;
  float* feat_out = featB;
  const int off_[4] = {0, 128, 384, 896};

  for (int st = 0; st < 4; ++st){
    int Sin = 2048 >> st, Sout = 1024 >> st, C = 32 << st, Cout = 2*C, cfg = st + 1;
    float* xout = (st & 1) ? xyzB : xyzA;

    if      (st == 0) k_fps<8><<<BB, 256, 0, stream>>>(xin, xout, fpsi);
    else if (st == 1) k_fps<4><<<BB, 256, 0, stream>>>(xin, xout, fpsi);
    else if (st == 2) k_fps<2><<<BB, 256, 0, stream>>>(xin, xout, fpsi);
    else              k_fps<1><<<BB, 256, 0, stream>>>(xin, xout, fpsi);

    int gfs_bs = (C < 64) ? 64 : ((C > 256) ? 256 : C);
    k_gather_fs<<<BB*Sout, gfs_bs, 0, stream>>>(feat_in, fpsi, feats, Sout, C, Sin);

    int knn_blocks = BB * (Sout / 16);
    if      (st == 0) k_knn2<2048><<<knn_blocks, 256, 0, stream>>>(xin, xout, knni, Sout);
    else if (st == 1) k_knn2<1024><<<knn_blocks, 256, 0, stream>>>(xin, xout, knni, Sout);
    else if (st == 2) k_knn2< 512><<<knn_blocks, 256, 0, stream>>>(xin, xout, knni, Sout);
    else              k_knn2< 256><<<knn_blocks, 256, 0, stream>>>(xin, xout, knni, Sout);

    hipMemsetAsync(ws + OFF_STATS, 0, SZ_STATS, stream);
    k_stats<<<BB*(Sout/8), 256, 0, stream>>>(xin, xout, feat_in, feats, knni, stats, Sin, Sout, C);
    k_finalize<<<1, 256, 0, stream>>>(stats, par, Sout, C);
    k_main<<<BB*Sout, Cout, 0, stream>>>(xin, xout, feat_in, feats, knni, par,
                                         fv + h_FVOFF[cfg], omd + h_OMOFF[cfg],
                                         omf + h_OMOFF[cfg], feat_out, Sin, Sout, C);
    k_stageout<<<dim3(BB, Cout/64), 64, 0, stream>>>(feat_out, out, Sout, Cout, off_[st]);

    xin = xout;
    float* t2 = feat_in; feat_in = feat_out; feat_out = t2;
  }
}

// Round 5
// 4017.226 us; speedup vs baseline: 4.0019x; 1.0674x over previous
//
#include <hip/hip_runtime.h>
#include <math.h>

#define USE_FMA_DOT 1   // einsum dot rounding: 1 = Eigen-style fma chain, 0 = separate roundings

constexpr int BB  = 32;
constexpr int N0  = 2048;
constexpr int KNN = 32;
constexpr float SIGMA_ = 0.26f;
constexpr float BASELINE_ = 0.1f;
constexpr float SCALING_ = 10.0f;
constexpr float EPS_ = 1e-6f;

// embedding configs: cfg0 = initial od=32; cfg1..4 = stage out_dims 64,128,256,512
__device__ __constant__ const int c_OD[5]    = {32,64,128,256,512};
__device__ __constant__ const int c_FD[5]    = {11,22,43,86,171};
__device__ __constant__ const int c_FVOFF[5] = {0,11,33,76,162};
__device__ __constant__ const int c_OMOFF[5] = {0,32,96,224,480};
static const int h_FVOFF[5] = {0,11,33,76,162};
static const int h_OMOFF[5] = {0,32,96,224,480};

// ---------------- workspace layout (bytes) ----------------
constexpr size_t ALGN(size_t x){ return (x + 255) & ~(size_t)255; }
constexpr size_t SZ_FEAT  = (size_t)BB*2048*32*4;   // 8 MB (holds any stage's feat: all are 2M floats)
constexpr size_t OFF_FEATA = 0;
constexpr size_t OFF_FEATB = OFF_FEATA + SZ_FEAT;
constexpr size_t SZ_FEATS  = (size_t)BB*1024*32*4;  // 4 MB (B*S_out*C_in == 1M floats each stage)
constexpr size_t OFF_FEATS = OFF_FEATB + SZ_FEAT;
constexpr size_t SZ_KNNI   = (size_t)BB*1024*KNN*4; // 4 MB
constexpr size_t OFF_KNNI  = OFF_FEATS + SZ_FEATS;
constexpr size_t SZ_XYZ    = (size_t)BB*1024*3*4;
constexpr size_t OFF_XYZA  = OFF_KNNI + SZ_KNNI;
constexpr size_t OFF_XYZB  = OFF_XYZA + ALGN(SZ_XYZ);
constexpr size_t SZ_FPSI   = (size_t)BB*1024*4;
constexpr size_t OFF_FPSI  = OFF_XYZB + ALGN(SZ_XYZ);
constexpr size_t SZ_STATS  = 8192*8;                // f64: xs[32][32][3], xq, fs[32][32], fq
constexpr size_t OFF_STATS = OFF_FPSI + ALGN(SZ_FPSI);
constexpr size_t SZ_STATS0 = 192*8;
constexpr size_t OFF_STATS0= OFF_STATS + SZ_STATS;
constexpr size_t OFF_FV    = OFF_STATS0 + ALGN(SZ_STATS0);
constexpr size_t OFF_OMD   = OFF_FV  + ALGN(333*4);
constexpr size_t OFF_OMF   = OFF_OMD + ALGN(992*4);
constexpr size_t OFF_PAR0  = OFF_OMF + ALGN(992*4);
constexpr size_t OFF_PAR   = OFF_PAR0 + 256;
constexpr size_t WS_NEED   = OFF_PAR + 512;

// ---------------- exact-arithmetic helpers (match XLA CPU elementwise rounding) ----------------
__device__ __forceinline__ float sq3_ref(float x, float y, float z) {
#pragma clang fp contract(off)
  float a = x*x, b = y*y, c = z*z;
  return (a + b) + c;
}
__device__ __forceinline__ float dist3_ref(float ax,float ay,float az,float bx,float by,float bz){
#pragma clang fp contract(off)
  float dx = ax-bx, dy = ay-by, dz = az-bz;
  float a = dx*dx, b = dy*dy, c = dz*dz;
  return (a + b) + c;
}
__device__ __forceinline__ float knn_dist(float qx,float qy,float qz,float ssrc,
                                          float px,float py,float pz){
#pragma clang fp contract(off)
  float sdst = (px*px + py*py) + pz*pz;
#if USE_FMA_DOT
  float dot = __builtin_fmaf(qz, pz, __builtin_fmaf(qy, py, qx*px));
#else
  float dot = (qx*px + qy*py) + qz*pz;
#endif
  float m = -2.0f * dot;
  return (m + ssrc) + sdst;
}

// ---------------- table init (numpy linspace semantics in f64) ----------------
__global__ void k_init_tables(float* __restrict__ fv, int* __restrict__ omd, int* __restrict__ omf){
  for (int cfg = 0; cfg < 5; ++cfg){
    int od = c_OD[cfg], fd = c_FD[cfg], fn = fd*3;
    double stepv = 2.0 / (double)(fd + 1);
    for (int f = threadIdx.x; f < fd; f += blockDim.x)
      fv[c_FVOFF[cfg] + f] = (float)((double)(f+1) * stepv + (-1.0));
    double stepi = (double)(fn - 1) / (double)(od - 1);
    for (int j = threadIdx.x; j < od; j += blockDim.x){
      int q = (j == od-1) ? (fn-1) : (int)floor((double)j * stepi);
      omd[c_OMOFF[cfg] + j] = q / fd;
      omf[c_OMOFF[cfg] + j] = q - (q/fd)*fd;
    }
  }
}

// ---------------- initial gstd (per (b,c) sum/sumsq over N) ----------------
__global__ void k_stats0(const float* __restrict__ xyz, double* __restrict__ s0){
  int e = blockIdx.x, b = e/3, c = e%3, t = threadIdx.x;
  double s = 0.0, ss = 0.0;
  for (int n = t; n < N0; n += blockDim.x){
    double v = (double)xyz[((size_t)b*N0 + n)*3 + c];
    s += v; ss += v*v;
  }
  __shared__ double ls[256], lq[256];
  ls[t] = s; lq[t] = ss; __syncthreads();
  for (int w = 128; w > 0; w >>= 1){
    if (t < w){ ls[t] += ls[t+w]; lq[t] += lq[t+w]; }
    __syncthreads();
  }
  if (t == 0){ s0[e*2] = ls[0]; s0[e*2+1] = lq[0]; }
}

__global__ void k_finalize0(const double* __restrict__ s0, float* __restrict__ par0){
  __shared__ double acc[96];
  int t = threadIdx.x;
  if (t < 96){
    double s = s0[t*2], ss = s0[t*2+1];
    double var = (ss - s*s/(double)N0) / (double)(N0 - 1);
    acc[t] = sqrt(var < 0.0 ? 0.0 : var);
  }
  __syncthreads();
  if (t == 0){
    double g = 0.0;
    for (int i = 0; i < 96; ++i) g += acc[i];
    float gstd = (float)(g / 96.0);
    float asig = SIGMA_ * (1.0f + gstd);
    float dn = asig + EPS_;
    float blend = 1.0f / (1.0f + expf(-(gstd - BASELINE_)*SCALING_));
    par0[0] = 1.0f/dn; par0[1] = blend; par0[2] = 1.0f - blend;
  }
}

// ---------------- initial embedding: feat0[b,n,0..31] ----------------
__global__ void k_embed0(const float* __restrict__ xyz, float* __restrict__ feat,
                         const float* __restrict__ par0, const float* __restrict__ fv,
                         const int* __restrict__ omd, const int* __restrict__ omf){
  int e = blockIdx.x*blockDim.x + threadIdx.x;
  if (e >= BB*N0) return;
  float x0 = xyz[(size_t)e*3], x1 = xyz[(size_t)e*3+1], x2 = xyz[(size_t)e*3+2];
  float invdn = par0[0], blend = par0[1], omb = par0[2];
  float* out = &feat[(size_t)e*32];
  #pragma unroll 8
  for (int j = 0; j < 32; ++j){
    int dj = omd[j];
    float xv = (dj == 0) ? x0 : ((dj == 1) ? x1 : x2);
    float tt = (xv - fv[omf[j]]) * invdn;
    out[j] = blend*__expf(-0.5f*tt*tt) + omb*__cosf(tt);
  }
}

// ---------------- FPS v2: ONE WAVE per batch — no barriers, packed-u64 argmax ----------------
// key = (f32_bits(dist) << 32) | ~j ; dist >= 0 so bits are monotone. max-key reduce
// == (max dist, ties -> smallest j) == jnp.argmax first-index semantics.
// dist3_ref arithmetic identical to v1 -> bit-identical selection trajectory.
template<int N>
__launch_bounds__(64)
__global__ void k_fps2(const float* __restrict__ xyz, float* __restrict__ xyz_out,
                       int* __restrict__ fps_idx){
  constexpr int NL = N / 64;
  constexpr int SOUT = N / 2;
  int b = blockIdx.x, lane = threadIdx.x;
  const float* xb = xyz + (size_t)b*N*3;
  __shared__ float xl[N*3];
  for (int i = lane; i < N*3; i += 64) xl[i] = xb[i];
  __syncthreads();
  float px[NL], py[NL], pz[NL], dist[NL];
  #pragma unroll
  for (int i = 0; i < NL; ++i){
    int j = i*64 + lane;
    px[i] = xl[j*3]; py[i] = xl[j*3+1]; pz[i] = xl[j*3+2];
    dist[i] = INFINITY;
  }
  float cx = xl[0], cy = xl[1], cz = xl[2];
  if (lane == 0){
    fps_idx[b*1024] = 0;
    size_t o = (size_t)b*SOUT*3;
    xyz_out[o] = cx; xyz_out[o+1] = cy; xyz_out[o+2] = cz;
  }
  for (int step = 1; step < SOUT; ++step){
    float bv; int bi;
    #pragma unroll
    for (int i = 0; i < NL; ++i){
      float d = dist3_ref(px[i], py[i], pz[i], cx, cy, cz);
      float nd = fminf(dist[i], d);
      dist[i] = nd;
      if (i == 0){ bv = nd; bi = 0; }
      else if (nd > bv){ bv = nd; bi = i; }   // strict > keeps smallest i (ascending j)
    }
    int j = bi*64 + lane;
    unsigned long long key = ((unsigned long long)__float_as_uint(bv) << 32)
                           | (unsigned)(~(unsigned)j);
    #pragma unroll
    for (int m = 1; m < 64; m <<= 1){
      unsigned long long o = __shfl_xor(key, m);
      key = (o > key) ? o : key;
    }
    int wi = (int)(~(unsigned)(key & 0xFFFFFFFFULL));
    cx = xl[wi*3]; cy = xl[wi*3+1]; cz = xl[wi*3+2];
    if (lane == 0){
      fps_idx[b*1024 + step] = wi;
      size_t o = (size_t)b*SOUT*3 + (size_t)step*3;
      xyz_out[o] = cx; xyz_out[o+1] = cy; xyz_out[o+2] = cz;
    }
  }
}

// ---------------- gather feat_s (flat elementwise; total = BB*32768 every stage) ----------------
__global__ void k_gather_fs(const float* __restrict__ feat, const int* __restrict__ fps_idx,
                            float* __restrict__ feat_s, int cShift, int sMask, int S_out, int C, int S_in){
  int e = blockIdx.x*blockDim.x + threadIdx.x;   // e < BB*32768, exact grid
  int c = e & (C - 1);
  int rs = e >> cShift;
  int s = rs & sMask;
  int b = rs >> (15 - cShift);                   // S_out*C == 32768 always
  int idx = fps_idx[b*1024 + s];
  feat_s[e] = feat[((size_t)b*S_in + idx)*C + c];
}

// ---------------- KNN v2: one wave per query, branchless exact 32-round extraction ----------------
// key = (monotone_bits(dist) << 32) | j  -> ascending u64 order == lax.top_k order
// (dist ascending, ties -> smaller index). Distance arithmetic identical to v1.
template<int N>
__launch_bounds__(256)
__global__ void k_knn2(const float* __restrict__ xyz, const float* __restrict__ xyz_s,
                       int* __restrict__ knn_idx, int S_out){
  constexpr int NL = N / 64;       // candidates per lane
  constexpr int QB = 16;           // queries per block (4 waves x 4 queries)
  constexpr int QW = QB / 4;
  __shared__ float xl[N*3];
  int nb = S_out / QB;
  int b = blockIdx.x / nb, chunk = blockIdx.x - b*nb;
  int t = threadIdx.x, w = t >> 6, lane = t & 63;
  const float* xb = xyz + (size_t)b*N*3;
  for (int i = t; i < N*3; i += 256) xl[i] = xb[i];
  __syncthreads();
  for (int r = 0; r < QW; ++r){
    int s = chunk*QB + w*QW + r;
    const float* q = &xyz_s[((size_t)b*S_out + s)*3];
    float qx = q[0], qy = q[1], qz = q[2];
    float ssrc = sq3_ref(qx, qy, qz);
    unsigned long long cur[NL];
    #pragma unroll
    for (int i = 0; i < NL; ++i){
      int j = i*64 + lane;
      float d = knn_dist(qx, qy, qz, ssrc, xl[j*3], xl[j*3+1], xl[j*3+2]);
      unsigned u = __float_as_uint(d);
      u ^= (unsigned)((int)u >> 31) | 0x80000000u;   // monotone float->uint
      cur[i] = ((unsigned long long)u << 32) | (unsigned)j;
    }
    unsigned long long keep = 0;
    for (int kr = 0; kr < KNN; ++kr){
      unsigned long long m = cur[0];
      #pragma unroll
      for (int i = 1; i < NL; ++i) m = (cur[i] < m) ? cur[i] : m;
      #pragma unroll
      for (int msk = 1; msk < 64; msk <<= 1){
        unsigned long long o = __shfl_xor(m, msk);
        m = (o < m) ? o : m;
      }
      #pragma unroll
      for (int i = 0; i < NL; ++i) if (cur[i] == m) cur[i] = ~0ULL;  // unique (idx in key)
      if (lane == kr) keep = m;
    }
    if (lane < KNN)
      knn_idx[((size_t)b*S_out + s)*KNN + lane] = (int)(unsigned)(keep & 0xFFFFFFFFULL);
  }
}

// ---------------- per-k stats (f64), 64 queries per block -> 8x fewer atomics ----------------
__launch_bounds__(256)
__global__ void k_stats(const float* __restrict__ xyz, const float* __restrict__ xyz_s,
                        const float* __restrict__ feat, const float* __restrict__ feat_s,
                        const int* __restrict__ knn_idx, double* __restrict__ acc,
                        int S_in, int S_out, int C){
  int nb = S_out / 64;
  int b = blockIdx.x / nb, chunk = blockIdx.x - b*nb;
  int t = threadIdx.x, k = t & 31, sl = t >> 5;
  __shared__ double ls[256][8];
  int k2 = t & 31, v = t >> 5;
  double a = 0.0;
  for (int sub = 0; sub < 8; ++sub){
    int s = chunk*64 + sub*8 + sl;
    int idx = knn_idx[((size_t)b*S_out + s)*KNN + k];
    const float* p  = &xyz[((size_t)b*S_in + idx)*3];
    const float* c0 = &xyz_s[((size_t)b*S_out + s)*3];
    double vs[8];
    #pragma unroll
    for (int c = 0; c < 3; ++c){
      float d = p[c] - c0[c];
      double dd = (double)d;
      vs[c] = dd; vs[3+c] = dd*dd;
    }
    const float* fp = &feat[((size_t)b*S_in + idx)*C];
    const float* fc = &feat_s[((size_t)b*S_out + s)*C];
    double fs = 0.0, fq = 0.0;
    for (int c = 0; c < C; ++c){
      float d = fp[c] - fc[c];
      double dd = (double)d;
      fs += dd; fq += dd*dd;
    }
    vs[6] = fs; vs[7] = fq;
    __syncthreads();
    #pragma unroll
    for (int vv = 0; vv < 8; ++vv) ls[t][vv] = vs[vv];
    __syncthreads();
    #pragma unroll
    for (int s2 = 0; s2 < 8; ++s2) a += ls[k2 + 32*s2][v];
  }
  double* tgt;
  if (v < 3)       tgt = &acc[((size_t)(b*32 + k2))*3 + v];
  else if (v < 6)  tgt = &acc[3072 + ((size_t)(b*32 + k2))*3 + (v-3)];
  else if (v == 6) tgt = &acc[6144 + b*32 + k2];
  else             tgt = &acc[7168 + b*32 + k2];
  atomicAdd(tgt, a);
}

// ---------------- finalize: stds (per-k), gstd, asig, blend ----------------
__launch_bounds__(256)
__global__ void k_finalize(const double* __restrict__ acc, float* __restrict__ par,
                           int S_out, int C){
  __shared__ double invx_d[32];
  __shared__ double bcstd[96];
  int t = threadIdx.x;
  if (t < 32){
    double S = 0.0, Q = 0.0;
    for (int b = 0; b < BB; ++b)
      #pragma unroll
      for (int c = 0; c < 3; ++c){
        S += acc[((size_t)(b*32 + t))*3 + c];
        Q += acc[3072 + ((size_t)(b*32 + t))*3 + c];
      }
    double n = (double)BB * S_out * 3;
    double var = (Q - S*S/n) / (n - 1.0);
    float sd = (float)sqrt(var < 0.0 ? 0.0 : var);
    sd = fmaxf(sd, 1e-5f);
    par[t] = sd;                       // divisor for xyz normalize (exact f32 div later)
    invx_d[t] = 1.0 / (double)sd;
  } else if (t < 64){
    int k = t - 32;
    double S = 0.0, Q = 0.0;
    for (int b = 0; b < BB; ++b){
      S += acc[6144 + b*32 + k];
      Q += acc[7168 + b*32 + k];
    }
    double n = (double)BB * S_out * C;
    double var = (Q - S*S/n) / (n - 1.0);
    float sd = (float)sqrt(var < 0.0 ? 0.0 : var);
    sd = fmaxf(sd, 1e-5f);
    par[32 + k] = 1.0f / sd;           // reciprocal for feat normalize
  }
  __syncthreads();
  if (t < 96){
    int b = t/3, c = t - (t/3)*3;
    double S1 = 0.0, S2 = 0.0;
    for (int k = 0; k < 32; ++k){
      double iv = invx_d[k];
      S1 += acc[((size_t)(b*32 + k))*3 + c] * iv;
      S2 += acc[3072 + ((size_t)(b*32 + k))*3 + c] * iv*iv;
    }
    double m = (double)S_out * KNN;
    double var = (S2 - S1*S1/m) / (m - 1.0);
    bcstd[t] = sqrt(var < 0.0 ? 0.0 : var);
  }
  __syncthreads();
  if (t == 0){
    double g = 0.0;
    for (int i = 0; i < 96; ++i) g += bcstd[i];
    float gstd = (float)(g / 96.0);
    float asig = SIGMA_ * (1.0f + gstd);
    float dn = asig + EPS_;
    float blend = 1.0f / (1.0f + expf(-(gstd - BASELINE_)*SCALING_));
    par[64] = 1.0f/dn; par[65] = blend; par[66] = 1.0f - blend;
  }
}

// ---------------- main: pe + feature concat + (mean+max over K) + gelu ----------------
__launch_bounds__(512)
__global__ void k_main(const float* __restrict__ xyz, const float* __restrict__ xyz_s,
                       const float* __restrict__ feat, const float* __restrict__ feat_s,
                       const int* __restrict__ knn_idx, const float* __restrict__ par,
                       const float* __restrict__ fv, const int* __restrict__ omd,
                       const int* __restrict__ omf, float* __restrict__ feat_out,
                       int S_in, int S_out, int C){
  int b = blockIdx.x / S_out, s = blockIdx.x - b*S_out;
  int t = threadIdx.x, Cout = blockDim.x;
  __shared__ float nx[KNN][4];
  __shared__ int idxs[KNN];
  const float* cs = &xyz_s[((size_t)b*S_out + s)*3];
  for (int e = t; e < 96; e += Cout){
    int k = e/3, c = e - k*3;
    int ix = knn_idx[((size_t)b*S_out + s)*KNN + k];
    if (c == 0) idxs[k] = ix;
    float p = xyz[((size_t)b*S_in + ix)*3 + c];
    nx[k][c] = (p - cs[c]) / par[k];   // exact f32 division, matches reference d/std
  }
  __syncthreads();
  int dimj = omd[t], fij = omf[t];
  float fvv = fv[fij];
  float invdn = par[64], blend = par[65], omb = par[66];
  const float* fsrow = &feat_s[((size_t)b*S_out + s)*C];
  bool lo = (t < C);
  float fsj = lo ? fsrow[t] : fsrow[t - C];
  const float* fb = &feat[(size_t)b*S_in*C];
  float acc = 0.0f, mx = -INFINITY;
  for (int k = 0; k < KNN; ++k){
    float fc;
    if (lo){
      float f = fb[(size_t)idxs[k]*C + t];
      fc = (f - fsj) * par[32 + k];
    } else {
      fc = fsj;
    }
    float xv = nx[k][dimj];
    float tt = (xv - fvv) * invdn;
    float pe = blend*__expf(-0.5f*tt*tt) + omb*__cosf(tt);
    float w = (fc + pe) * pe;
    acc += w;
    mx = fmaxf(mx, w);
  }
  float pooled = acc * (1.0f/KNN) + mx;
  float g = 0.5f * pooled * (1.0f + erff(pooled / 1.41421356237f));
  feat_out[((size_t)b*S_out + s)*(size_t)(2*C) + t] = g;
}

// ---------------- per-stage output: max & mean over S ----------------
__global__ void k_stageout(const float* __restrict__ feat, float* __restrict__ out,
                           int S, int C, int off){
  int b = blockIdx.x;
  int c = blockIdx.y*64 + threadIdx.x;
  const float* f = &feat[(size_t)b*S*C + c];
  float mx = -INFINITY;
  double sm = 0.0;
  for (int s = 0; s < S; ++s){
    float v = f[(size_t)s*C];
    mx = fmaxf(mx, v);
    sm += (double)v;
  }
  out[(size_t)b*1920 + off + c] = mx;
  out[(size_t)b*1920 + off + C + c] = (float)(sm / (double)S);
}

// ---------------- host ----------------
extern "C" void kernel_launch(void* const* d_in, const int* in_sizes, int n_in,
                              void* d_out, int out_size, void* d_ws, size_t ws_size,
                              hipStream_t stream){
  if (ws_size < WS_NEED) return;
  const float* xyz0 = (const float*)d_in[0];
  float* out = (float*)d_out;
  char* ws = (char*)d_ws;

  float*  featA = (float*)(ws + OFF_FEATA);
  float*  featB = (float*)(ws + OFF_FEATB);
  float*  feats = (float*)(ws + OFF_FEATS);
  int*    knni  = (int*)  (ws + OFF_KNNI);
  float*  xyzA  = (float*)(ws + OFF_XYZA);
  float*  xyzB  = (float*)(ws + OFF_XYZB);
  int*    fpsi  = (int*)  (ws + OFF_FPSI);
  double* stats = (double*)(ws + OFF_STATS);
  double* s0    = (double*)(ws + OFF_STATS0);
  float*  fv    = (float*)(ws + OFF_FV);
  int*    omd   = (int*)  (ws + OFF_OMD);
  int*    omf   = (int*)  (ws + OFF_OMF);
  float*  par0  = (float*)(ws + OFF_PAR0);
  float*  par   = (float*)(ws + OFF_PAR);

  k_init_tables<<<1, 256, 0, stream>>>(fv, omd, omf);
  k_stats0<<<96, 256, 0, stream>>>(xyz0, s0);
  k_finalize0<<<1, 128, 0, stream>>>(s0, par0);
  k_embed0<<<(BB*N0)/256, 256, 0, stream>>>(xyz0, featA, par0, fv, omd, omf);

  const float* xin = xyz0;
  float* feat_in  = featA;
  float* feat_out = featB;
  const int off_[4] = {0, 128, 384, 896};

  for (int st = 0; st < 4; ++st){
    int Sin = 2048 >> st, Sout = 1024 >> st, C = 32 << st, Cout = 2*C, cfg = st + 1;
    float* xout = (st & 1) ? xyzB : xyzA;

    if      (st == 0) k_fps2<2048><<<BB, 64, 0, stream>>>(xin, xout, fpsi);
    else if (st == 1) k_fps2<1024><<<BB, 64, 0, stream>>>(xin, xout, fpsi);
    else if (st == 2) k_fps2< 512><<<BB, 64, 0, stream>>>(xin, xout, fpsi);
    else              k_fps2< 256><<<BB, 64, 0, stream>>>(xin, xout, fpsi);

    // gather feat_s: flat, total = BB*Sout*C = BB*32768 for every stage
    k_gather_fs<<<(BB*32768)/256, 256, 0, stream>>>(feat_in, fpsi, feats,
                                                    5 + st, Sout - 1, Sout, C, Sin);

    int knn_blocks = BB * (Sout / 16);
    if      (st == 0) k_knn2<2048><<<knn_blocks, 256, 0, stream>>>(xin, xout, knni, Sout);
    else if (st == 1) k_knn2<1024><<<knn_blocks, 256, 0, stream>>>(xin, xout, knni, Sout);
    else if (st == 2) k_knn2< 512><<<knn_blocks, 256, 0, stream>>>(xin, xout, knni, Sout);
    else              k_knn2< 256><<<knn_blocks, 256, 0, stream>>>(xin, xout, knni, Sout);

    hipMemsetAsync(ws + OFF_STATS, 0, SZ_STATS, stream);
    k_stats<<<BB*(Sout/64), 256, 0, stream>>>(xin, xout, feat_in, feats, knni, stats, Sin, Sout, C);
    k_finalize<<<1, 256, 0, stream>>>(stats, par, Sout, C);
    k_main<<<BB*Sout, Cout, 0, stream>>>(xin, xout, feat_in, feats, knni, par,
                                         fv + h_FVOFF[cfg], omd + h_OMOFF[cfg],
                                         omf + h_OMOFF[cfg], feat_out, Sin, Sout, C);
    k_stageout<<<dim3(BB, Cout/64), 64, 0, stream>>>(feat_out, out, Sout, Cout, off_[st]);

    xin = xout;
    float* t2 = feat_in; feat_in = feat_out; feat_out = t2;
  }
}

// Round 6
// 3518.950 us; speedup vs baseline: 4.5686x; 1.1416x over previous
//
#include <hip/hip_runtime.h>
#include <math.h>

#define USE_FMA_DOT 1   // einsum dot rounding: 1 = Eigen-style fma chain, 0 = separate roundings

constexpr int BB  = 32;
constexpr int N0  = 2048;
constexpr int KNN = 32;
constexpr float SIGMA_ = 0.26f;
constexpr float BASELINE_ = 0.1f;
constexpr float SCALING_ = 10.0f;
constexpr float EPS_ = 1e-6f;

// embedding configs: cfg0 = initial od=32; cfg1..4 = stage out_dims 64,128,256,512
__device__ __constant__ const int c_OD[5]    = {32,64,128,256,512};
__device__ __constant__ const int c_FD[5]    = {11,22,43,86,171};
__device__ __constant__ const int c_FVOFF[5] = {0,11,33,76,162};
__device__ __constant__ const int c_OMOFF[5] = {0,32,96,224,480};
static const int h_FVOFF[5] = {0,11,33,76,162};
static const int h_OMOFF[5] = {0,32,96,224,480};

// ---------------- workspace layout (bytes) ----------------
constexpr size_t ALGN(size_t x){ return (x + 255) & ~(size_t)255; }
constexpr size_t SZ_FEAT  = (size_t)BB*2048*32*4;   // 8 MB (holds any stage's feat: all are 2M floats)
constexpr size_t OFF_FEATA = 0;
constexpr size_t OFF_FEATB = OFF_FEATA + SZ_FEAT;
constexpr size_t SZ_FEATS  = (size_t)BB*1024*32*4;  // 4 MB (B*S_out*C_in == 1M floats each stage)
constexpr size_t OFF_FEATS = OFF_FEATB + SZ_FEAT;
constexpr size_t SZ_KNNI   = (size_t)BB*1024*KNN*4; // 4 MB
constexpr size_t OFF_KNNI  = OFF_FEATS + SZ_FEATS;
constexpr size_t SZ_XYZ    = (size_t)BB*1024*3*4;
constexpr size_t OFF_XYZA  = OFF_KNNI + SZ_KNNI;
constexpr size_t OFF_XYZB  = OFF_XYZA + ALGN(SZ_XYZ);
constexpr size_t SZ_FPSI   = (size_t)BB*1024*4;
constexpr size_t OFF_FPSI  = OFF_XYZB + ALGN(SZ_XYZ);
constexpr size_t SZ_STATS  = 8192*8;                // f64: xs[32][32][3], xq, fs[32][32], fq
constexpr size_t OFF_STATS = OFF_FPSI + ALGN(SZ_FPSI);
constexpr size_t SZ_STATS0 = 192*8;
constexpr size_t OFF_STATS0= OFF_STATS + SZ_STATS;
constexpr size_t OFF_FV    = OFF_STATS0 + ALGN(SZ_STATS0);
constexpr size_t OFF_OMD   = OFF_FV  + ALGN(333*4);
constexpr size_t OFF_OMF   = OFF_OMD + ALGN(992*4);
constexpr size_t OFF_PAR0  = OFF_OMF + ALGN(992*4);
constexpr size_t OFF_PAR   = OFF_PAR0 + 256;
constexpr size_t WS_NEED   = OFF_PAR + 512;

// ---------------- exact-arithmetic helpers (match XLA CPU elementwise rounding) ----------------
__device__ __forceinline__ float sq3_ref(float x, float y, float z) {
#pragma clang fp contract(off)
  float a = x*x, b = y*y, c = z*z;
  return (a + b) + c;
}
__device__ __forceinline__ float dist3_ref(float ax,float ay,float az,float bx,float by,float bz){
#pragma clang fp contract(off)
  float dx = ax-bx, dy = ay-by, dz = az-bz;
  float a = dx*dx, b = dy*dy, c = dz*dz;
  return (a + b) + c;
}
__device__ __forceinline__ float knn_dist(float qx,float qy,float qz,float ssrc,
                                          float px,float py,float pz){
#pragma clang fp contract(off)
  float sdst = (px*px + py*py) + pz*pz;
#if USE_FMA_DOT
  float dot = __builtin_fmaf(qz, pz, __builtin_fmaf(qy, py, qx*px));
#else
  float dot = (qx*px + qy*py) + qz*pz;
#endif
  float m = -2.0f * dot;
  return (m + ssrc) + sdst;
}

// ---------------- table init (numpy linspace semantics in f64) ----------------
__global__ void k_init_tables(float* __restrict__ fv, int* __restrict__ omd, int* __restrict__ omf){
  for (int cfg = 0; cfg < 5; ++cfg){
    int od = c_OD[cfg], fd = c_FD[cfg], fn = fd*3;
    double stepv = 2.0 / (double)(fd + 1);
    for (int f = threadIdx.x; f < fd; f += blockDim.x)
      fv[c_FVOFF[cfg] + f] = (float)((double)(f+1) * stepv + (-1.0));
    double stepi = (double)(fn - 1) / (double)(od - 1);
    for (int j = threadIdx.x; j < od; j += blockDim.x){
      int q = (j == od-1) ? (fn-1) : (int)floor((double)j * stepi);
      omd[c_OMOFF[cfg] + j] = q / fd;
      omf[c_OMOFF[cfg] + j] = q - (q/fd)*fd;
    }
  }
}

// ---------------- initial gstd (per (b,c) sum/sumsq over N) ----------------
__global__ void k_stats0(const float* __restrict__ xyz, double* __restrict__ s0){
  int e = blockIdx.x, b = e/3, c = e%3, t = threadIdx.x;
  double s = 0.0, ss = 0.0;
  for (int n = t; n < N0; n += blockDim.x){
    double v = (double)xyz[((size_t)b*N0 + n)*3 + c];
    s += v; ss += v*v;
  }
  __shared__ double ls[256], lq[256];
  ls[t] = s; lq[t] = ss; __syncthreads();
  for (int w = 128; w > 0; w >>= 1){
    if (t < w){ ls[t] += ls[t+w]; lq[t] += lq[t+w]; }
    __syncthreads();
  }
  if (t == 0){ s0[e*2] = ls[0]; s0[e*2+1] = lq[0]; }
}

__global__ void k_finalize0(const double* __restrict__ s0, float* __restrict__ par0){
  __shared__ double acc[96];
  int t = threadIdx.x;
  if (t < 96){
    double s = s0[t*2], ss = s0[t*2+1];
    double var = (ss - s*s/(double)N0) / (double)(N0 - 1);
    acc[t] = sqrt(var < 0.0 ? 0.0 : var);
  }
  __syncthreads();
  if (t == 0){
    double g = 0.0;
    for (int i = 0; i < 96; ++i) g += acc[i];
    float gstd = (float)(g / 96.0);
    float asig = SIGMA_ * (1.0f + gstd);
    float dn = asig + EPS_;
    float blend = 1.0f / (1.0f + expf(-(gstd - BASELINE_)*SCALING_));
    par0[0] = 1.0f/dn; par0[1] = blend; par0[2] = 1.0f - blend;
  }
}

// ---------------- initial embedding: feat0[b,n,0..31] ----------------
__global__ void k_embed0(const float* __restrict__ xyz, float* __restrict__ feat,
                         const float* __restrict__ par0, const float* __restrict__ fv,
                         const int* __restrict__ omd, const int* __restrict__ omf){
  int e = blockIdx.x*blockDim.x + threadIdx.x;
  if (e >= BB*N0) return;
  float x0 = xyz[(size_t)e*3], x1 = xyz[(size_t)e*3+1], x2 = xyz[(size_t)e*3+2];
  float invdn = par0[0], blend = par0[1], omb = par0[2];
  float* out = &feat[(size_t)e*32];
  #pragma unroll 8
  for (int j = 0; j < 32; ++j){
    int dj = omd[j];
    float xv = (dj == 0) ? x0 : ((dj == 1) ? x1 : x2);
    float tt = (xv - fv[omf[j]]) * invdn;
    out[j] = blend*__expf(-0.5f*tt*tt) + omb*__cosf(tt);
  }
}

// ---------------- FPS v2: ONE WAVE per batch — no barriers, packed-u64 argmax ----------------
// key = (f32_bits(dist) << 32) | ~j ; dist >= 0 so bits are monotone. max-key reduce
// == (max dist, ties -> smallest j) == jnp.argmax first-index semantics.
// dist3_ref arithmetic identical to v1 -> bit-identical selection trajectory.
// __launch_bounds__(64,1): 1 wave/EU -> full VGPR budget; stage 0 needs 128+ regs
// for the 4x32 coordinate/dist arrays (92-reg default spilled to scratch, r5 post-mortem).
template<int N>
__launch_bounds__(64, 1)
__global__ void k_fps2(const float* __restrict__ xyz, float* __restrict__ xyz_out,
                       int* __restrict__ fps_idx){
  constexpr int NL = N / 64;
  constexpr int SOUT = N / 2;
  int b = blockIdx.x, lane = threadIdx.x;
  const float* xb = xyz + (size_t)b*N*3;
  __shared__ float xl[N*3];
  for (int i = lane; i < N*3; i += 64) xl[i] = xb[i];
  __syncthreads();
  float px[NL], py[NL], pz[NL], dist[NL];
  #pragma unroll
  for (int i = 0; i < NL; ++i){
    int j = i*64 + lane;
    px[i] = xl[j*3]; py[i] = xl[j*3+1]; pz[i] = xl[j*3+2];
    dist[i] = INFINITY;
  }
  float cx = xl[0], cy = xl[1], cz = xl[2];
  if (lane == 0){
    fps_idx[b*1024] = 0;
    size_t o = (size_t)b*SOUT*3;
    xyz_out[o] = cx; xyz_out[o+1] = cy; xyz_out[o+2] = cz;
  }
  for (int step = 1; step < SOUT; ++step){
    float bv; int bi;
    #pragma unroll
    for (int i = 0; i < NL; ++i){
      float d = dist3_ref(px[i], py[i], pz[i], cx, cy, cz);
      float nd = fminf(dist[i], d);
      dist[i] = nd;
      if (i == 0){ bv = nd; bi = 0; }
      else if (nd > bv){ bv = nd; bi = i; }   // strict > keeps smallest i (ascending j)
    }
    int j = bi*64 + lane;
    unsigned long long key = ((unsigned long long)__float_as_uint(bv) << 32)
                           | (unsigned)(~(unsigned)j);
    #pragma unroll
    for (int m = 1; m < 64; m <<= 1){
      unsigned long long o = __shfl_xor(key, m);
      key = (o > key) ? o : key;
    }
    int wi = (int)(~(unsigned)(key & 0xFFFFFFFFULL));
    cx = xl[wi*3]; cy = xl[wi*3+1]; cz = xl[wi*3+2];
    if (lane == 0){
      fps_idx[b*1024 + step] = wi;
      size_t o = (size_t)b*SOUT*3 + (size_t)step*3;
      xyz_out[o] = cx; xyz_out[o+1] = cy; xyz_out[o+2] = cz;
    }
  }
}

// ---------------- gather feat_s (flat elementwise; total = BB*32768 every stage) ----------------
__global__ void k_gather_fs(const float* __restrict__ feat, const int* __restrict__ fps_idx,
                            float* __restrict__ feat_s, int cShift, int sMask, int S_out, int C, int S_in){
  int e = blockIdx.x*blockDim.x + threadIdx.x;   // e < BB*32768, exact grid
  int c = e & (C - 1);
  int rs = e >> cShift;
  int s = rs & sMask;
  int b = rs >> (15 - cShift);                   // S_out*C == 32768 always
  int idx = fps_idx[b*1024 + s];
  feat_s[e] = feat[((size_t)b*S_in + idx)*C + c];
}

// ---------------- KNN v2: one wave per query, branchless exact 32-round extraction ----------------
// key = (monotone_bits(dist) << 32) | j  -> ascending u64 order == lax.top_k order
// (dist ascending, ties -> smaller index). Distance arithmetic identical to v1.
template<int N>
__launch_bounds__(256)
__global__ void k_knn2(const float* __restrict__ xyz, const float* __restrict__ xyz_s,
                       int* __restrict__ knn_idx, int S_out){
  constexpr int NL = N / 64;       // candidates per lane
  constexpr int QB = 16;           // queries per block (4 waves x 4 queries)
  constexpr int QW = QB / 4;
  __shared__ float xl[N*3];
  int nb = S_out / QB;
  int b = blockIdx.x / nb, chunk = blockIdx.x - b*nb;
  int t = threadIdx.x, w = t >> 6, lane = t & 63;
  const float* xb = xyz + (size_t)b*N*3;
  for (int i = t; i < N*3; i += 256) xl[i] = xb[i];
  __syncthreads();
  for (int r = 0; r < QW; ++r){
    int s = chunk*QB + w*QW + r;
    const float* q = &xyz_s[((size_t)b*S_out + s)*3];
    float qx = q[0], qy = q[1], qz = q[2];
    float ssrc = sq3_ref(qx, qy, qz);
    unsigned long long cur[NL];
    #pragma unroll
    for (int i = 0; i < NL; ++i){
      int j = i*64 + lane;
      float d = knn_dist(qx, qy, qz, ssrc, xl[j*3], xl[j*3+1], xl[j*3+2]);
      unsigned u = __float_as_uint(d);
      u ^= (unsigned)((int)u >> 31) | 0x80000000u;   // monotone float->uint
      cur[i] = ((unsigned long long)u << 32) | (unsigned)j;
    }
    unsigned long long keep = 0;
    for (int kr = 0; kr < KNN; ++kr){
      unsigned long long m = cur[0];
      #pragma unroll
      for (int i = 1; i < NL; ++i) m = (cur[i] < m) ? cur[i] : m;
      #pragma unroll
      for (int msk = 1; msk < 64; msk <<= 1){
        unsigned long long o = __shfl_xor(m, msk);
        m = (o < m) ? o : m;
      }
      #pragma unroll
      for (int i = 0; i < NL; ++i) if (cur[i] == m) cur[i] = ~0ULL;  // unique (idx in key)
      if (lane == kr) keep = m;
    }
    if (lane < KNN)
      knn_idx[((size_t)b*S_out + s)*KNN + lane] = (int)(unsigned)(keep & 0xFFFFFFFFULL);
  }
}

// ---------------- per-k stats v3: register accumulation, no LDS, shfl+atomics ----------------
// grid = BB*8 blocks of 256 (8 s-slots x 32 k). Each thread accumulates its 8 f64
// stats over S/64 queries, combines lane<->lane^32 (same k), low half-wave atomics.
__launch_bounds__(256)
__global__ void k_stats(const float* __restrict__ xyz, const float* __restrict__ xyz_s,
                        const float* __restrict__ feat, const float* __restrict__ feat_s,
                        const int* __restrict__ knn_idx, double* __restrict__ acc,
                        int S_in, int S_out, int C){
  int b = blockIdx.x >> 3, chunk = blockIdx.x & 7;
  int t = threadIdx.x, k = t & 31, sl = t >> 5;     // sl in 0..7
  double xs0=0,xs1=0,xs2=0,xq0=0,xq1=0,xq2=0,fs=0,fq=0;
  int iters = S_out >> 6;                           // >= 2 for all stages
  int base = chunk * (S_out >> 3) + sl;
  int C4 = C >> 2;
  for (int it = 0; it < iters; ++it){
    int s = base + it*8;
    int idx = knn_idx[((size_t)b*S_out + s)*KNN + k];
    const float* p  = &xyz[((size_t)b*S_in + idx)*3];
    const float* c0 = &xyz_s[((size_t)b*S_out + s)*3];
    float d0 = p[0]-c0[0], d1 = p[1]-c0[1], d2 = p[2]-c0[2];
    double e0 = (double)d0, e1 = (double)d1, e2 = (double)d2;
    xs0 += e0; xs1 += e1; xs2 += e2;
    xq0 += e0*e0; xq1 += e1*e1; xq2 += e2*e2;
    const float4* fp = (const float4*)&feat[((size_t)b*S_in + idx)*C];
    const float4* fc = (const float4*)&feat_s[((size_t)b*S_out + s)*C];
    for (int c4 = 0; c4 < C4; ++c4){
      float4 a4 = fp[c4], b4 = fc[c4];
      double u;
      u = (double)(a4.x - b4.x); fs += u; fq += u*u;
      u = (double)(a4.y - b4.y); fs += u; fq += u*u;
      u = (double)(a4.z - b4.z); fs += u; fq += u*u;
      u = (double)(a4.w - b4.w); fs += u; fq += u*u;
    }
  }
  // combine lane l with l^32 (same k, paired s-slot) within each wave
  xs0 += __shfl_xor(xs0, 32); xs1 += __shfl_xor(xs1, 32); xs2 += __shfl_xor(xs2, 32);
  xq0 += __shfl_xor(xq0, 32); xq1 += __shfl_xor(xq1, 32); xq2 += __shfl_xor(xq2, 32);
  fs  += __shfl_xor(fs,  32); fq  += __shfl_xor(fq,  32);
  if ((t & 32) == 0){
    size_t bk = (size_t)(b*32 + k);
    atomicAdd(&acc[bk*3 + 0], xs0);
    atomicAdd(&acc[bk*3 + 1], xs1);
    atomicAdd(&acc[bk*3 + 2], xs2);
    atomicAdd(&acc[3072 + bk*3 + 0], xq0);
    atomicAdd(&acc[3072 + bk*3 + 1], xq1);
    atomicAdd(&acc[3072 + bk*3 + 2], xq2);
    atomicAdd(&acc[6144 + bk], fs);
    atomicAdd(&acc[7168 + bk], fq);
  }
}

// ---------------- finalize: stds (per-k), gstd, asig, blend ----------------
__launch_bounds__(256)
__global__ void k_finalize(const double* __restrict__ acc, float* __restrict__ par,
                           int S_out, int C){
  __shared__ double invx_d[32];
  __shared__ double bcstd[96];
  int t = threadIdx.x;
  if (t < 32){
    double S = 0.0, Q = 0.0;
    for (int b = 0; b < BB; ++b)
      #pragma unroll
      for (int c = 0; c < 3; ++c){
        S += acc[((size_t)(b*32 + t))*3 + c];
        Q += acc[3072 + ((size_t)(b*32 + t))*3 + c];
      }
    double n = (double)BB * S_out * 3;
    double var = (Q - S*S/n) / (n - 1.0);
    float sd = (float)sqrt(var < 0.0 ? 0.0 : var);
    sd = fmaxf(sd, 1e-5f);
    par[t] = sd;                       // divisor for xyz normalize (exact f32 div later)
    invx_d[t] = 1.0 / (double)sd;
  } else if (t < 64){
    int k = t - 32;
    double S = 0.0, Q = 0.0;
    for (int b = 0; b < BB; ++b){
      S += acc[6144 + b*32 + k];
      Q += acc[7168 + b*32 + k];
    }
    double n = (double)BB * S_out * C;
    double var = (Q - S*S/n) / (n - 1.0);
    float sd = (float)sqrt(var < 0.0 ? 0.0 : var);
    sd = fmaxf(sd, 1e-5f);
    par[32 + k] = 1.0f / sd;           // reciprocal for feat normalize
  }
  __syncthreads();
  if (t < 96){
    int b = t/3, c = t - (t/3)*3;
    double S1 = 0.0, S2 = 0.0;
    for (int k = 0; k < 32; ++k){
      double iv = invx_d[k];
      S1 += acc[((size_t)(b*32 + k))*3 + c] * iv;
      S2 += acc[3072 + ((size_t)(b*32 + k))*3 + c] * iv*iv;
    }
    double m = (double)S_out * KNN;
    double var = (S2 - S1*S1/m) / (m - 1.0);
    bcstd[t] = sqrt(var < 0.0 ? 0.0 : var);
  }
  __syncthreads();
  if (t == 0){
    double g = 0.0;
    for (int i = 0; i < 96; ++i) g += bcstd[i];
    float gstd = (float)(g / 96.0);
    float asig = SIGMA_ * (1.0f + gstd);
    float dn = asig + EPS_;
    float blend = 1.0f / (1.0f + expf(-(gstd - BASELINE_)*SCALING_));
    par[64] = 1.0f/dn; par[65] = blend; par[66] = 1.0f - blend;
  }
}

// ---------------- main: pe + feature concat + (mean+max over K) + gelu ----------------
__launch_bounds__(512)
__global__ void k_main(const float* __restrict__ xyz, const float* __restrict__ xyz_s,
                       const float* __restrict__ feat, const float* __restrict__ feat_s,
                       const int* __restrict__ knn_idx, const float* __restrict__ par,
                       const float* __restrict__ fv, const int* __restrict__ omd,
                       const int* __restrict__ omf, float* __restrict__ feat_out,
                       int S_in, int S_out, int C){
  int b = blockIdx.x / S_out, s = blockIdx.x - b*S_out;
  int t = threadIdx.x, Cout = blockDim.x;
  __shared__ float nx[KNN][4];
  __shared__ int idxs[KNN];
  const float* cs = &xyz_s[((size_t)b*S_out + s)*3];
  for (int e = t; e < 96; e += Cout){
    int k = e/3, c = e - k*3;
    int ix = knn_idx[((size_t)b*S_out + s)*KNN + k];
    if (c == 0) idxs[k] = ix;
    float p = xyz[((size_t)b*S_in + ix)*3 + c];
    nx[k][c] = (p - cs[c]) / par[k];   // exact f32 division, matches reference d/std
  }
  __syncthreads();
  int dimj = omd[t], fij = omf[t];
  float fvv = fv[fij];
  float invdn = par[64], blend = par[65], omb = par[66];
  const float* fsrow = &feat_s[((size_t)b*S_out + s)*C];
  bool lo = (t < C);
  float fsj = lo ? fsrow[t] : fsrow[t - C];
  const float* fb = &feat[(size_t)b*S_in*C];
  float acc = 0.0f, mx = -INFINITY;
  for (int k = 0; k < KNN; ++k){
    float fc;
    if (lo){
      float f = fb[(size_t)idxs[k]*C + t];
      fc = (f - fsj) * par[32 + k];
    } else {
      fc = fsj;
    }
    float xv = nx[k][dimj];
    float tt = (xv - fvv) * invdn;
    float pe = blend*__expf(-0.5f*tt*tt) + omb*__cosf(tt);
    float w = (fc + pe) * pe;
    acc += w;
    mx = fmaxf(mx, w);
  }
  float pooled = acc * (1.0f/KNN) + mx;
  float g = 0.5f * pooled * (1.0f + erff(pooled / 1.41421356237f));
  feat_out[((size_t)b*S_out + s)*(size_t)(2*C) + t] = g;
}

// ---------------- per-stage output: max & mean over S ----------------
__global__ void k_stageout(const float* __restrict__ feat, float* __restrict__ out,
                           int S, int C, int off){
  int b = blockIdx.x;
  int c = blockIdx.y*64 + threadIdx.x;
  const float* f = &feat[(size_t)b*S*C + c];
  float mx = -INFINITY;
  double sm = 0.0;
  for (int s = 0; s < S; ++s){
    float v = f[(size_t)s*C];
    mx = fmaxf(mx, v);
    sm += (double)v;
  }
  out[(size_t)b*1920 + off + c] = mx;
  out[(size_t)b*1920 + off + C + c] = (float)(sm / (double)S);
}

// ---------------- host ----------------
extern "C" void kernel_launch(void* const* d_in, const int* in_sizes, int n_in,
                              void* d_out, int out_size, void* d_ws, size_t ws_size,
                              hipStream_t stream){
  if (ws_size < WS_NEED) return;
  const float* xyz0 = (const float*)d_in[0];
  float* out = (float*)d_out;
  char* ws = (char*)d_ws;

  float*  featA = (float*)(ws + OFF_FEATA);
  float*  featB = (float*)(ws + OFF_FEATB);
  float*  feats = (float*)(ws + OFF_FEATS);
  int*    knni  = (int*)  (ws + OFF_KNNI);
  float*  xyzA  = (float*)(ws + OFF_XYZA);
  float*  xyzB  = (float*)(ws + OFF_XYZB);
  int*    fpsi  = (int*)  (ws + OFF_FPSI);
  double* stats = (double*)(ws + OFF_STATS);
  double* s0    = (double*)(ws + OFF_STATS0);
  float*  fv    = (float*)(ws + OFF_FV);
  int*    omd   = (int*)  (ws + OFF_OMD);
  int*    omf   = (int*)  (ws + OFF_OMF);
  float*  par0  = (float*)(ws + OFF_PAR0);
  float*  par   = (float*)(ws + OFF_PAR);

  k_init_tables<<<1, 256, 0, stream>>>(fv, omd, omf);
  k_stats0<<<96, 256, 0, stream>>>(xyz0, s0);
  k_finalize0<<<1, 128, 0, stream>>>(s0, par0);
  k_embed0<<<(BB*N0)/256, 256, 0, stream>>>(xyz0, featA, par0, fv, omd, omf);

  const float* xin = xyz0;
  float* feat_in  = featA;
  float* feat_out = featB;
  const int off_[4] = {0, 128, 384, 896};

  for (int st = 0; st < 4; ++st){
    int Sin = 2048 >> st, Sout = 1024 >> st, C = 32 << st, Cout = 2*C, cfg = st + 1;
    float* xout = (st & 1) ? xyzB : xyzA;

    if      (st == 0) k_fps2<2048><<<BB, 64, 0, stream>>>(xin, xout, fpsi);
    else if (st == 1) k_fps2<1024><<<BB, 64, 0, stream>>>(xin, xout, fpsi);
    else if (st == 2) k_fps2< 512><<<BB, 64, 0, stream>>>(xin, xout, fpsi);
    else              k_fps2< 256><<<BB, 64, 0, stream>>>(xin, xout, fpsi);

    // gather feat_s: flat, total = BB*Sout*C = BB*32768 for every stage
    k_gather_fs<<<(BB*32768)/256, 256, 0, stream>>>(feat_in, fpsi, feats,
                                                    5 + st, Sout - 1, Sout, C, Sin);

    int knn_blocks = BB * (Sout / 16);
    if      (st == 0) k_knn2<2048><<<knn_blocks, 256, 0, stream>>>(xin, xout, knni, Sout);
    else if (st == 1) k_knn2<1024><<<knn_blocks, 256, 0, stream>>>(xin, xout, knni, Sout);
    else if (st == 2) k_knn2< 512><<<knn_blocks, 256, 0, stream>>>(xin, xout, knni, Sout);
    else              k_knn2< 256><<<knn_blocks, 256, 0, stream>>>(xin, xout, knni, Sout);

    hipMemsetAsync(ws + OFF_STATS, 0, SZ_STATS, stream);
    k_stats<<<BB*8, 256, 0, stream>>>(xin, xout, feat_in, feats, knni, stats, Sin, Sout, C);
    k_finalize<<<1, 256, 0, stream>>>(stats, par, Sout, C);
    k_main<<<BB*Sout, Cout, 0, stream>>>(xin, xout, feat_in, feats, knni, par,
                                         fv + h_FVOFF[cfg], omd + h_OMOFF[cfg],
                                         omf + h_OMOFF[cfg], feat_out, Sin, Sout, C);
    k_stageout<<<dim3(BB, Cout/64), 64, 0, stream>>>(feat_out, out, Sout, Cout, off_[st]);

    xin = xout;
    float* t2 = feat_in; feat_in = feat_out; feat_out = t2;
  }
}

// Round 9
// 3160.844 us; speedup vs baseline: 5.0862x; 1.1133x over previous
//
#include <hip/hip_runtime.h>
#include <math.h>

#define USE_FMA_DOT 1   // einsum dot rounding: 1 = Eigen-style fma chain, 0 = separate roundings

constexpr int BB  = 32;
constexpr int N0  = 2048;
constexpr int KNN = 32;
constexpr float SIGMA_ = 0.26f;
constexpr float BASELINE_ = 0.1f;
constexpr float SCALING_ = 10.0f;
constexpr float EPS_ = 1e-6f;

// embedding configs: cfg0 = initial od=32; cfg1..4 = stage out_dims 64,128,256,512
__device__ __constant__ const int c_OD[5]    = {32,64,128,256,512};
__device__ __constant__ const int c_FD[5]    = {11,22,43,86,171};
__device__ __constant__ const int c_FVOFF[5] = {0,11,33,76,162};
__device__ __constant__ const int c_OMOFF[5] = {0,32,96,224,480};
static const int h_FVOFF[5] = {0,11,33,76,162};
static const int h_OMOFF[5] = {0,32,96,224,480};

// ---------------- workspace layout (bytes) ----------------
constexpr size_t ALGN(size_t x){ return (x + 255) & ~(size_t)255; }
constexpr size_t SZ_FEAT  = (size_t)BB*2048*32*4;   // 8 MB (holds any stage's feat: all are 2M floats)
constexpr size_t OFF_FEATA = 0;
constexpr size_t OFF_FEATB = OFF_FEATA + SZ_FEAT;
constexpr size_t SZ_FEATS  = (size_t)BB*1024*32*4;  // 4 MB (B*S_out*C_in == 1M floats each stage)
constexpr size_t OFF_FEATS = OFF_FEATB + SZ_FEAT;
constexpr size_t SZ_KNNI   = (size_t)BB*1024*KNN*4; // 4 MB
constexpr size_t OFF_KNNI  = OFF_FEATS + SZ_FEATS;
constexpr size_t SZ_XYZ    = (size_t)BB*1024*3*4;
constexpr size_t OFF_XYZA  = OFF_KNNI + SZ_KNNI;
constexpr size_t OFF_XYZB  = OFF_XYZA + ALGN(SZ_XYZ);
constexpr size_t SZ_FPSI   = (size_t)BB*1024*4;
constexpr size_t OFF_FPSI  = OFF_XYZB + ALGN(SZ_XYZ);
constexpr size_t SZ_STATS  = 8192*8;                // f64: xs[32][32][3], xq, fs[32][32], fq
constexpr size_t OFF_STATS = OFF_FPSI + ALGN(SZ_FPSI);
constexpr size_t SZ_STATS0 = 192*8;
constexpr size_t OFF_STATS0= OFF_STATS + SZ_STATS;
constexpr size_t OFF_FV    = OFF_STATS0 + ALGN(SZ_STATS0);
constexpr size_t OFF_OMD   = OFF_FV  + ALGN(333*4);
constexpr size_t OFF_OMF   = OFF_OMD + ALGN(992*4);
constexpr size_t OFF_PAR0  = OFF_OMF + ALGN(992*4);
constexpr size_t OFF_PAR   = OFF_PAR0 + 256;
constexpr size_t WS_NEED   = OFF_PAR + 512;

// ---------------- exact-arithmetic helpers (match XLA CPU elementwise rounding) ----------------
__device__ __forceinline__ float sq3_ref(float x, float y, float z) {
#pragma clang fp contract(off)
  float a = x*x, b = y*y, c = z*z;
  return (a + b) + c;
}
__device__ __forceinline__ float dist3_ref(float ax,float ay,float az,float bx,float by,float bz){
#pragma clang fp contract(off)
  float dx = ax-bx, dy = ay-by, dz = az-bz;
  float a = dx*dx, b = dy*dy, c = dz*dz;
  return (a + b) + c;
}
__device__ __forceinline__ float knn_dist(float qx,float qy,float qz,float ssrc,
                                          float px,float py,float pz){
#pragma clang fp contract(off)
  float sdst = (px*px + py*py) + pz*pz;
#if USE_FMA_DOT
  float dot = __builtin_fmaf(qz, pz, __builtin_fmaf(qy, py, qx*px));
#else
  float dot = (qx*px + qy*py) + qz*pz;
#endif
  float m = -2.0f * dot;
  return (m + ssrc) + sdst;
}

// ---------------- table init (numpy linspace semantics in f64) ----------------
__global__ void k_init_tables(float* __restrict__ fv, int* __restrict__ omd, int* __restrict__ omf){
  for (int cfg = 0; cfg < 5; ++cfg){
    int od = c_OD[cfg], fd = c_FD[cfg], fn = fd*3;
    double stepv = 2.0 / (double)(fd + 1);
    for (int f = threadIdx.x; f < fd; f += blockDim.x)
      fv[c_FVOFF[cfg] + f] = (float)((double)(f+1) * stepv + (-1.0));
    double stepi = (double)(fn - 1) / (double)(od - 1);
    for (int j = threadIdx.x; j < od; j += blockDim.x){
      int q = (j == od-1) ? (fn-1) : (int)floor((double)j * stepi);
      omd[c_OMOFF[cfg] + j] = q / fd;
      omf[c_OMOFF[cfg] + j] = q - (q/fd)*fd;
    }
  }
}

// ---------------- initial gstd (per (b,c) sum/sumsq over N) ----------------
__global__ void k_stats0(const float* __restrict__ xyz, double* __restrict__ s0){
  int e = blockIdx.x, b = e/3, c = e%3, t = threadIdx.x;
  double s = 0.0, ss = 0.0;
  for (int n = t; n < N0; n += blockDim.x){
    double v = (double)xyz[((size_t)b*N0 + n)*3 + c];
    s += v; ss += v*v;
  }
  __shared__ double ls[256], lq[256];
  ls[t] = s; lq[t] = ss; __syncthreads();
  for (int w = 128; w > 0; w >>= 1){
    if (t < w){ ls[t] += ls[t+w]; lq[t] += lq[t+w]; }
    __syncthreads();
  }
  if (t == 0){ s0[e*2] = ls[0]; s0[e*2+1] = lq[0]; }
}

__global__ void k_finalize0(const double* __restrict__ s0, float* __restrict__ par0){
  __shared__ double acc[96];
  int t = threadIdx.x;
  if (t < 96){
    double s = s0[t*2], ss = s0[t*2+1];
    double var = (ss - s*s/(double)N0) / (double)(N0 - 1);
    acc[t] = sqrt(var < 0.0 ? 0.0 : var);
  }
  __syncthreads();
  if (t == 0){
    double g = 0.0;
    for (int i = 0; i < 96; ++i) g += acc[i];
    float gstd = (float)(g / 96.0);
    float asig = SIGMA_ * (1.0f + gstd);
    float dn = asig + EPS_;
    float blend = 1.0f / (1.0f + expf(-(gstd - BASELINE_)*SCALING_));
    par0[0] = 1.0f/dn; par0[1] = blend; par0[2] = 1.0f - blend;
  }
}

// ---------------- initial embedding: feat0[b,n,0..31] ----------------
__global__ void k_embed0(const float* __restrict__ xyz, float* __restrict__ feat,
                         const float* __restrict__ par0, const float* __restrict__ fv,
                         const int* __restrict__ omd, const int* __restrict__ omf){
  int e = blockIdx.x*blockDim.x + threadIdx.x;
  if (e >= BB*N0) return;
  float x0 = xyz[(size_t)e*3], x1 = xyz[(size_t)e*3+1], x2 = xyz[(size_t)e*3+2];
  float invdn = par0[0], blend = par0[1], omb = par0[2];
  float* out = &feat[(size_t)e*32];
  #pragma unroll 8
  for (int j = 0; j < 32; ++j){
    int dj = omd[j];
    float xv = (dj == 0) ? x0 : ((dj == 1) ? x1 : x2);
    float tt = (xv - fv[omf[j]]) * invdn;
    out[j] = blend*__expf(-0.5f*tt*tt) + omb*__cosf(tt);
  }
}

// ---------------- FPS v3: ONE WAVE per batch, coords PINNED in registers ----------------
// key = (f32_bits(dist) << 32) | ~j ; dist >= 0 so bits are monotone. max-key reduce
// == (max dist, ties -> smallest j) == jnp.argmax first-index semantics.
// dist3_ref arithmetic identical to v1 -> bit-identical selection trajectory.
// r6 post-mortem: compiler REMATERIALIZED px/py/pz from LDS every step (VGPR=92,
// ~32 ds_read/lane/step). The asm pin makes them opaque register values it cannot
// re-load; (64,1) gives the full 512-VGPR budget for the ~160 live regs.
template<int N>
__launch_bounds__(64, 1)
__global__ void k_fps2(const float* __restrict__ xyz, float* __restrict__ xyz_out,
                       int* __restrict__ fps_idx){
  constexpr int NL = N / 64;
  constexpr int SOUT = N / 2;
  int b = blockIdx.x, lane = threadIdx.x;
  const float* xb = xyz + (size_t)b*N*3;
  __shared__ float xl[N*3];
  for (int i = lane; i < N*3; i += 64) xl[i] = xb[i];
  __syncthreads();
  float px[NL], py[NL], pz[NL], dist[NL];
  #pragma unroll
  for (int i = 0; i < NL; ++i){
    int j = i*64 + lane;
    px[i] = xl[j*3]; py[i] = xl[j*3+1]; pz[i] = xl[j*3+2];
    dist[i] = INFINITY;
  }
  // pin coordinates into VGPRs (defeat LDS rematerialization; rule #17 idiom)
  #pragma unroll
  for (int i = 0; i < NL; ++i)
    asm volatile("" : "+v"(px[i]), "+v"(py[i]), "+v"(pz[i]));
  float cx = xl[0], cy = xl[1], cz = xl[2];
  if (lane == 0){
    fps_idx[b*1024] = 0;
    size_t o = (size_t)b*SOUT*3;
    xyz_out[o] = cx; xyz_out[o+1] = cy; xyz_out[o+2] = cz;
  }
  for (int step = 1; step < SOUT; ++step){
    float bv; int bi;
    #pragma unroll
    for (int i = 0; i < NL; ++i){
      float d = dist3_ref(px[i], py[i], pz[i], cx, cy, cz);
      float nd = fminf(dist[i], d);
      dist[i] = nd;
      if (i == 0){ bv = nd; bi = 0; }
      else if (nd > bv){ bv = nd; bi = i; }   // strict > keeps smallest i (ascending j)
    }
    int j = bi*64 + lane;
    unsigned long long key = ((unsigned long long)__float_as_uint(bv) << 32)
                           | (unsigned)(~(unsigned)j);
    #pragma unroll
    for (int m = 1; m < 64; m <<= 1){
      unsigned long long o = __shfl_xor(key, m);
      key = (o > key) ? o : key;
    }
    int wi = (int)(~(unsigned)(key & 0xFFFFFFFFULL));
    cx = xl[wi*3]; cy = xl[wi*3+1]; cz = xl[wi*3+2];
    if (lane == 0){
      fps_idx[b*1024 + step] = wi;
      size_t o = (size_t)b*SOUT*3 + (size_t)step*3;
      xyz_out[o] = cx; xyz_out[o+1] = cy; xyz_out[o+2] = cz;
    }
  }
}

// ---------------- gather feat_s (flat elementwise; total = BB*32768 every stage) ----------------
__global__ void k_gather_fs(const float* __restrict__ feat, const int* __restrict__ fps_idx,
                            float* __restrict__ feat_s, int cShift, int sMask, int S_out, int C, int S_in){
  int e = blockIdx.x*blockDim.x + threadIdx.x;   // e < BB*32768, exact grid
  int c = e & (C - 1);
  int rs = e >> cShift;
  int s = rs & sMask;
  int b = rs >> (15 - cShift);                   // S_out*C == 32768 always
  int idx = fps_idx[b*1024 + s];
  feat_s[e] = feat[((size_t)b*S_in + idx)*C + c];
}

// ---------------- KNN v2: one wave per query, branchless exact 32-round extraction ----------------
// key = (monotone_bits(dist) << 32) | j  -> ascending u64 order == lax.top_k order
// (dist ascending, ties -> smaller index). Distance arithmetic identical to v1.
template<int N>
__launch_bounds__(256)
__global__ void k_knn2(const float* __restrict__ xyz, const float* __restrict__ xyz_s,
                       int* __restrict__ knn_idx, int S_out){
  constexpr int NL = N / 64;       // candidates per lane
  constexpr int QB = 16;           // queries per block (4 waves x 4 queries)
  constexpr int QW = QB / 4;
  __shared__ float xl[N*3];
  int nb = S_out / QB;
  int b = blockIdx.x / nb, chunk = blockIdx.x - b*nb;
  int t = threadIdx.x, w = t >> 6, lane = t & 63;
  const float* xb = xyz + (size_t)b*N*3;
  for (int i = t; i < N*3; i += 256) xl[i] = xb[i];
  __syncthreads();
  for (int r = 0; r < QW; ++r){
    int s = chunk*QB + w*QW + r;
    const float* q = &xyz_s[((size_t)b*S_out + s)*3];
    float qx = q[0], qy = q[1], qz = q[2];
    float ssrc = sq3_ref(qx, qy, qz);
    unsigned long long cur[NL];
    #pragma unroll
    for (int i = 0; i < NL; ++i){
      int j = i*64 + lane;
      float d = knn_dist(qx, qy, qz, ssrc, xl[j*3], xl[j*3+1], xl[j*3+2]);
      unsigned u = __float_as_uint(d);
      u ^= (unsigned)((int)u >> 31) | 0x80000000u;   // monotone float->uint
      cur[i] = ((unsigned long long)u << 32) | (unsigned)j;
    }
    unsigned long long keep = 0;
    for (int kr = 0; kr < KNN; ++kr){
      unsigned long long m = cur[0];
      #pragma unroll
      for (int i = 1; i < NL; ++i) m = (cur[i] < m) ? cur[i] : m;
      #pragma unroll
      for (int msk = 1; msk < 64; msk <<= 1){
        unsigned long long o = __shfl_xor(m, msk);
        m = (o < m) ? o : m;
      }
      #pragma unroll
      for (int i = 0; i < NL; ++i) if (cur[i] == m) cur[i] = ~0ULL;  // unique (idx in key)
      if (lane == kr) keep = m;
    }
    if (lane < KNN)
      knn_idx[((size_t)b*S_out + s)*KNN + lane] = (int)(unsigned)(keep & 0xFFFFFFFFULL);
  }
}

// ---------------- per-k stats v3: register accumulation, no LDS, shfl+atomics ----------------
__launch_bounds__(256)
__global__ void k_stats(const float* __restrict__ xyz, const float* __restrict__ xyz_s,
                        const float* __restrict__ feat, const float* __restrict__ feat_s,
                        const int* __restrict__ knn_idx, double* __restrict__ acc,
                        int S_in, int S_out, int C){
  int b = blockIdx.x >> 3, chunk = blockIdx.x & 7;
  int t = threadIdx.x, k = t & 31, sl = t >> 5;     // sl in 0..7
  double xs0=0,xs1=0,xs2=0,xq0=0,xq1=0,xq2=0,fs=0,fq=0;
  int iters = S_out >> 6;                           // >= 2 for all stages
  int base = chunk * (S_out >> 3) + sl;
  int C4 = C >> 2;
  for (int it = 0; it < iters; ++it){
    int s = base + it*8;
    int idx = knn_idx[((size_t)b*S_out + s)*KNN + k];
    const float* p  = &xyz[((size_t)b*S_in + idx)*3];
    const float* c0 = &xyz_s[((size_t)b*S_out + s)*3];
    float d0 = p[0]-c0[0], d1 = p[1]-c0[1], d2 = p[2]-c0[2];
    double e0 = (double)d0, e1 = (double)d1, e2 = (double)d2;
    xs0 += e0; xs1 += e1; xs2 += e2;
    xq0 += e0*e0; xq1 += e1*e1; xq2 += e2*e2;
    const float4* fp = (const float4*)&feat[((size_t)b*S_in + idx)*C];
    const float4* fc = (const float4*)&feat_s[((size_t)b*S_out + s)*C];
    for (int c4 = 0; c4 < C4; ++c4){
      float4 a4 = fp[c4], b4 = fc[c4];
      double u;
      u = (double)(a4.x - b4.x); fs += u; fq += u*u;
      u = (double)(a4.y - b4.y); fs += u; fq += u*u;
      u = (double)(a4.z - b4.z); fs += u; fq += u*u;
      u = (double)(a4.w - b4.w); fs += u; fq += u*u;
    }
  }
  // combine lane l with l^32 (same k, paired s-slot) within each wave
  xs0 += __shfl_xor(xs0, 32); xs1 += __shfl_xor(xs1, 32); xs2 += __shfl_xor(xs2, 32);
  xq0 += __shfl_xor(xq0, 32); xq1 += __shfl_xor(xq1, 32); xq2 += __shfl_xor(xq2, 32);
  fs  += __shfl_xor(fs,  32); fq  += __shfl_xor(fq,  32);
  if ((t & 32) == 0){
    size_t bk = (size_t)(b*32 + k);
    atomicAdd(&acc[bk*3 + 0], xs0);
    atomicAdd(&acc[bk*3 + 1], xs1);
    atomicAdd(&acc[bk*3 + 2], xs2);
    atomicAdd(&acc[3072 + bk*3 + 0], xq0);
    atomicAdd(&acc[3072 + bk*3 + 1], xq1);
    atomicAdd(&acc[3072 + bk*3 + 2], xq2);
    atomicAdd(&acc[6144 + bk], fs);
    atomicAdd(&acc[7168 + bk], fq);
  }
}

// ---------------- finalize: stds (per-k), gstd, asig, blend ----------------
__launch_bounds__(256)
__global__ void k_finalize(const double* __restrict__ acc, float* __restrict__ par,
                           int S_out, int C){
  __shared__ double invx_d[32];
  __shared__ double bcstd[96];
  int t = threadIdx.x;
  if (t < 32){
    double S = 0.0, Q = 0.0;
    for (int b = 0; b < BB; ++b)
      #pragma unroll
      for (int c = 0; c < 3; ++c){
        S += acc[((size_t)(b*32 + t))*3 + c];
        Q += acc[3072 + ((size_t)(b*32 + t))*3 + c];
      }
    double n = (double)BB * S_out * 3;
    double var = (Q - S*S/n) / (n - 1.0);
    float sd = (float)sqrt(var < 0.0 ? 0.0 : var);
    sd = fmaxf(sd, 1e-5f);
    par[t] = sd;                       // divisor for xyz normalize (exact f32 div later)
    invx_d[t] = 1.0 / (double)sd;
  } else if (t < 64){
    int k = t - 32;
    double S = 0.0, Q = 0.0;
    for (int b = 0; b < BB; ++b){
      S += acc[6144 + b*32 + k];
      Q += acc[7168 + b*32 + k];
    }
    double n = (double)BB * S_out * C;
    double var = (Q - S*S/n) / (n - 1.0);
    float sd = (float)sqrt(var < 0.0 ? 0.0 : var);
    sd = fmaxf(sd, 1e-5f);
    par[32 + k] = 1.0f / sd;           // reciprocal for feat normalize
  }
  __syncthreads();
  if (t < 96){
    int b = t/3, c = t - (t/3)*3;
    double S1 = 0.0, S2 = 0.0;
    for (int k = 0; k < 32; ++k){
      double iv = invx_d[k];
      S1 += acc[((size_t)(b*32 + k))*3 + c] * iv;
      S2 += acc[3072 + ((size_t)(b*32 + k))*3 + c] * iv*iv;
    }
    double m = (double)S_out * KNN;
    double var = (S2 - S1*S1/m) / (m - 1.0);
    bcstd[t] = sqrt(var < 0.0 ? 0.0 : var);
  }
  __syncthreads();
  if (t == 0){
    double g = 0.0;
    for (int i = 0; i < 96; ++i) g += bcstd[i];
    float gstd = (float)(g / 96.0);
    float asig = SIGMA_ * (1.0f + gstd);
    float dn = asig + EPS_;
    float blend = 1.0f / (1.0f + expf(-(gstd - BASELINE_)*SCALING_));
    par[64] = 1.0f/dn; par[65] = blend; par[66] = 1.0f - blend;
  }
}

// ---------------- main: pe + feature concat + (mean+max over K) + gelu ----------------
__launch_bounds__(512)
__global__ void k_main(const float* __restrict__ xyz, const float* __restrict__ xyz_s,
                       const float* __restrict__ feat, const float* __restrict__ feat_s,
                       const int* __restrict__ knn_idx, const float* __restrict__ par,
                       const float* __restrict__ fv, const int* __restrict__ omd,
                       const int* __restrict__ omf, float* __restrict__ feat_out,
                       int S_in, int S_out, int C){
  int b = blockIdx.x / S_out, s = blockIdx.x - b*S_out;
  int t = threadIdx.x, Cout = blockDim.x;
  __shared__ float nx[KNN][4];
  __shared__ int idxs[KNN];
  const float* cs = &xyz_s[((size_t)b*S_out + s)*3];
  for (int e = t; e < 96; e += Cout){
    int k = e/3, c = e - k*3;
    int ix = knn_idx[((size_t)b*S_out + s)*KNN + k];
    if (c == 0) idxs[k] = ix;
    float p = xyz[((size_t)b*S_in + ix)*3 + c];
    nx[k][c] = (p - cs[c]) / par[k];   // exact f32 division, matches reference d/std
  }
  __syncthreads();
  int dimj = omd[t], fij = omf[t];
  float fvv = fv[fij];
  float invdn = par[64], blend = par[65], omb = par[66];
  const float* fsrow = &feat_s[((size_t)b*S_out + s)*C];
  bool lo = (t < C);
  float fsj = lo ? fsrow[t] : fsrow[t - C];
  const float* fb = &feat[(size_t)b*S_in*C];
  float acc = 0.0f, mx = -INFINITY;
  for (int k = 0; k < KNN; ++k){
    float fc;
    if (lo){
      float f = fb[(size_t)idxs[k]*C + t];
      fc = (f - fsj) * par[32 + k];
    } else {
      fc = fsj;
    }
    float xv = nx[k][dimj];
    float tt = (xv - fvv) * invdn;
    float pe = blend*__expf(-0.5f*tt*tt) + omb*__cosf(tt);
    float w = (fc + pe) * pe;
    acc += w;
    mx = fmaxf(mx, w);
  }
  float pooled = acc * (1.0f/KNN) + mx;
  float g = 0.5f * pooled * (1.0f + erff(pooled / 1.41421356237f));
  feat_out[((size_t)b*S_out + s)*(size_t)(2*C) + t] = g;
}

// ---------------- per-stage output v2: coalesced max & mean over S ----------------
// block: 256 thr = 4 s-quarters x 64 channels; lanes read consecutive c (coalesced).
// f64 partial-sum reorder vs serial is invisible at f32 (continuous path).
__launch_bounds__(256)
__global__ void k_stageout(const float* __restrict__ feat, float* __restrict__ out,
                           int S, int C, int off){
  __shared__ float  lmx[4][64];
  __shared__ double lsm[4][64];
  int b = blockIdx.x;
  int lane = threadIdx.x & 63, q = threadIdx.x >> 6;
  int c = blockIdx.y*64 + lane;
  const float* f = &feat[(size_t)b*S*C + c];
  float mx = -INFINITY;
  double sm = 0.0;
  for (int s = q; s < S; s += 4){
    float v = f[(size_t)s*C];
    mx = fmaxf(mx, v);
    sm += (double)v;
  }
  lmx[q][lane] = mx; lsm[q][lane] = sm;
  __syncthreads();
  if (q == 0){
    #pragma unroll
    for (int w = 1; w < 4; ++w){
      mx = fmaxf(mx, lmx[w][lane]);
      sm += lsm[w][lane];
    }
    out[(size_t)b*1920 + off + c] = mx;
    out[(size_t)b*1920 + off + C + c] = (float)(sm / (double)S);
  }
}

// ---------------- host ----------------
extern "C" void kernel_launch(void* const* d_in, const int* in_sizes, int n_in,
                              void* d_out, int out_size, void* d_ws, size_t ws_size,
                              hipStream_t stream){
  if (ws_size < WS_NEED) return;
  const float* xyz0 = (const float*)d_in[0];
  float* out = (float*)d_out;
  char* ws = (char*)d_ws;

  float*  featA = (float*)(ws + OFF_FEATA);
  float*  featB = (float*)(ws + OFF_FEATB);
  float*  feats = (float*)(ws + OFF_FEATS);
  int*    knni  = (int*)  (ws + OFF_KNNI);
  float*  xyzA  = (float*)(ws + OFF_XYZA);
  float*  xyzB  = (float*)(ws + OFF_XYZB);
  int*    fpsi  = (int*)  (ws + OFF_FPSI);
  double* stats = (double*)(ws + OFF_STATS);
  double* s0    = (double*)(ws + OFF_STATS0);
  float*  fv    = (float*)(ws + OFF_FV);
  int*    omd   = (int*)  (ws + OFF_OMD);
  int*    omf   = (int*)  (ws + OFF_OMF);
  float*  par0  = (float*)(ws + OFF_PAR0);
  float*  par   = (float*)(ws + OFF_PAR);

  k_init_tables<<<1, 256, 0, stream>>>(fv, omd, omf);
  k_stats0<<<96, 256, 0, stream>>>(xyz0, s0);
  k_finalize0<<<1, 128, 0, stream>>>(s0, par0);
  k_embed0<<<(BB*N0)/256, 256, 0, stream>>>(xyz0, featA, par0, fv, omd, omf);

  const float* xin = xyz0;
  float* feat_in  = featA;
  float* feat_out = featB;
  const int off_[4] = {0, 128, 384, 896};

  for (int st = 0; st < 4; ++st){
    int Sin = 2048 >> st, Sout = 1024 >> st, C = 32 << st, Cout = 2*C, cfg = st + 1;
    float* xout = (st & 1) ? xyzB : xyzA;

    if      (st == 0) k_fps2<2048><<<BB, 64, 0, stream>>>(xin, xout, fpsi);
    else if (st == 1) k_fps2<1024><<<BB, 64, 0, stream>>>(xin, xout, fpsi);
    else if (st == 2) k_fps2< 512><<<BB, 64, 0, stream>>>(xin, xout, fpsi);
    else              k_fps2< 256><<<BB, 64, 0, stream>>>(xin, xout, fpsi);

    // gather feat_s: flat, total = BB*Sout*C = BB*32768 for every stage
    k_gather_fs<<<(BB*32768)/256, 256, 0, stream>>>(feat_in, fpsi, feats,
                                                    5 + st, Sout - 1, Sout, C, Sin);

    int knn_blocks = BB * (Sout / 16);
    if      (st == 0) k_knn2<2048><<<knn_blocks, 256, 0, stream>>>(xin, xout, knni, Sout);
    else if (st == 1) k_knn2<1024><<<knn_blocks, 256, 0, stream>>>(xin, xout, knni, Sout);
    else if (st == 2) k_knn2< 512><<<knn_blocks, 256, 0, stream>>>(xin, xout, knni, Sout);
    else              k_knn2< 256><<<knn_blocks, 256, 0, stream>>>(xin, xout, knni, Sout);

    hipMemsetAsync(ws + OFF_STATS, 0, SZ_STATS, stream);
    k_stats<<<BB*8, 256, 0, stream>>>(xin, xout, feat_in, feats, knni, stats, Sin, Sout, C);
    k_finalize<<<1, 256, 0, stream>>>(stats, par, Sout, C);
    k_main<<<BB*Sout, Cout, 0, stream>>>(xin, xout, feat_in, feats, knni, par,
                                         fv + h_FVOFF[cfg], omd + h_OMOFF[cfg],
                                         omf + h_OMOFF[cfg], feat_out, Sin, Sout, C);
    k_stageout<<<dim3(BB, Cout/64), 256, 0, stream>>>(feat_out, out, Sout, Cout, off_[st]);

    xin = xout;
    float* t2 = feat_in; feat_in = feat_out; feat_out = t2;
  }
}